// Round 1
// baseline (521.223 us; speedup 1.0000x reference)
//
#include <hip/hip_runtime.h>
#include <math.h>

#define N_NODES 50000
#define N_EDGES 800000
#define E_TOT (N_EDGES + N_NODES)

// ---------------- CSR build ----------------

__global__ void hist_k(const int* __restrict__ ei, int* __restrict__ cnt) {
    int e = blockIdx.x * blockDim.x + threadIdx.x;
    if (e < N_EDGES)      atomicAdd(&cnt[ei[N_EDGES + e]], 1);   // dst row of edge_index
    else if (e < E_TOT)   atomicAdd(&cnt[e - N_EDGES], 1);        // self loop
}

__global__ void scan_k(const int* __restrict__ cnt, int* __restrict__ offs,
                       int* __restrict__ cursor) {
    __shared__ int wsum[16];
    __shared__ int carry;
    int tid = threadIdx.x;
    if (tid == 0) { carry = 0; offs[0] = 0; cursor[0] = 0; }
    for (int base = 0; base < N_NODES; base += 1024) {
        __syncthreads();
        int i = base + tid;
        int v = (i < N_NODES) ? cnt[i] : 0;
        int lane = tid & 63, w = tid >> 6;
        int x = v;
        #pragma unroll
        for (int d = 1; d < 64; d <<= 1) {
            int y = __shfl_up(x, d);
            if (lane >= d) x += y;
        }
        if (lane == 63) wsum[w] = x;
        __syncthreads();
        if (tid == 0) {
            int s = 0;
            #pragma unroll
            for (int j = 0; j < 16; j++) { s += wsum[j]; wsum[j] = s; }
        }
        __syncthreads();
        int excl = carry + (w ? wsum[w - 1] : 0);
        if (i < N_NODES) { offs[i + 1] = excl + x; cursor[i + 1] = excl + x; }
        __syncthreads();
        if (tid == 0) carry += wsum[15];
    }
}

__global__ void scat_k(const int* __restrict__ ei, int* __restrict__ cursor,
                       int* __restrict__ csr) {
    int e = blockIdx.x * blockDim.x + threadIdx.x;
    int s, d;
    if (e < N_EDGES)      { s = ei[e]; d = ei[N_EDGES + e]; }
    else if (e < E_TOT)   { s = e - N_EDGES; d = s; }
    else return;
    int p = atomicAdd(&cursor[d], 1);
    csr[p] = s;
}

// ---------------- Layer 1 GEMM + fused attention scores ----------------
// h1[n][c] = sum_k x[n][k] * W1[k][c]      (c = head*32 + d, 256 cols)
// s1s[n][h] = sum_d h1[n][h*32+d]*a1_src[h][d]; s1d likewise.

__global__ __launch_bounds__(256) void gemm1_k(
        const float* __restrict__ x, const float* __restrict__ W1,
        const float* __restrict__ a1s, const float* __restrict__ a1d,
        float* __restrict__ h1, float* __restrict__ s1s, float* __restrict__ s1d) {
    __shared__ float xs[32][128];
    int tid = threadIdx.x;
    int row0 = blockIdx.x * 32;
    for (int i = tid; i < 32 * 32; i += 256) {      // 1024 float4 loads
        int r = i >> 5, q = i & 31;
        int row = row0 + r; if (row >= N_NODES) row = N_NODES - 1;
        float4 v = ((const float4*)(x + (size_t)row * 128))[q];
        *((float4*)&xs[r][q * 4]) = v;
    }
    __syncthreads();
    float acc[32];
    #pragma unroll
    for (int r = 0; r < 32; r++) acc[r] = 0.f;
    int c = tid;
    for (int k = 0; k < 128; k += 4) {
        float w0 = W1[(k + 0) * 256 + c];
        float w1 = W1[(k + 1) * 256 + c];
        float w2 = W1[(k + 2) * 256 + c];
        float w3 = W1[(k + 3) * 256 + c];
        #pragma unroll
        for (int r = 0; r < 32; r++) {
            float4 xv = *((const float4*)&xs[r][k]);
            acc[r] = fmaf(xv.x, w0, acc[r]);
            acc[r] = fmaf(xv.y, w1, acc[r]);
            acc[r] = fmaf(xv.z, w2, acc[r]);
            acc[r] = fmaf(xv.w, w3, acc[r]);
        }
    }
    float as = a1s[c], ad = a1d[c];
    int hh = tid >> 5;
    #pragma unroll 4
    for (int r = 0; r < 32; r++) {
        int row = row0 + r;
        float ps = acc[r] * as, pd = acc[r] * ad;
        #pragma unroll
        for (int mask = 16; mask >= 1; mask >>= 1) {
            ps += __shfl_xor(ps, mask);
            pd += __shfl_xor(pd, mask);
        }
        if (row < N_NODES) {
            h1[(size_t)row * 256 + c] = acc[r];
            if ((tid & 31) == 0) {
                s1s[row * 8 + hh] = ps;
                s1d[row * 8 + hh] = pd;
            }
        }
    }
}

// ---------------- Layer 1 aggregation (online softmax per dst node) ----------------

__global__ __launch_bounds__(256) void agg1_k(
        const int* __restrict__ csr, const int* __restrict__ offs,
        const float* __restrict__ h1, const float* __restrict__ s1s,
        const float* __restrict__ s1d, const float* __restrict__ b1,
        float* __restrict__ hr) {
    int n = blockIdx.x;
    int tid = threadIdx.x;
    int h = tid >> 5;
    int beg = offs[n], end = offs[n + 1];
    float sd = s1d[n * 8 + h];
    float m = -3.4e38f, denom = 0.f, acc = 0.f;
    for (int i = beg; i < end; i++) {
        int s = csr[i];
        float e = s1s[s * 8 + h] + sd;
        e = (e >= 0.f) ? e : 0.2f * e;
        float mn = fmaxf(m, e);
        float scale = __expf(m - mn);
        float p = __expf(e - mn);
        float hv = h1[(size_t)s * 256 + tid];
        denom = denom * scale + p;
        acc = acc * scale + p * hv;
        m = mn;
    }
    float v = acc / (denom + 1e-16f) + b1[tid];
    hr[(size_t)n * 256 + tid] = fmaxf(v, 0.f);   // ReLU between layers
}

// ---------------- Layer 2 GEMM + fused scores ----------------
// h2[n][c] = sum_k hr[n][k] * W2[k][c], c in [0,32)

__global__ __launch_bounds__(256) void gemm2_k(
        const float* __restrict__ hr, const float* __restrict__ W2,
        const float* __restrict__ a2s, const float* __restrict__ a2d,
        float* __restrict__ h2, float* __restrict__ s2s, float* __restrict__ s2d) {
    __shared__ float hs[32][256];
    int tid = threadIdx.x;
    int row0 = blockIdx.x * 32;
    for (int i = tid; i < 32 * 64; i += 256) {      // 2048 float4 loads
        int r = i >> 6, q = i & 63;
        int row = row0 + r; if (row >= N_NODES) row = N_NODES - 1;
        float4 v = ((const float4*)(hr + (size_t)row * 256))[q];
        *((float4*)&hs[r][q * 4]) = v;
    }
    __syncthreads();
    int c = tid & 31, g = tid >> 5;
    float acc[4] = {0.f, 0.f, 0.f, 0.f};
    for (int k = 0; k < 256; k++) {
        float wv = W2[k * 32 + c];
        #pragma unroll
        for (int j = 0; j < 4; j++) acc[j] += hs[g * 4 + j][k] * wv;
    }
    float av_s = a2s[c], av_d = a2d[c];
    #pragma unroll
    for (int j = 0; j < 4; j++) {
        int row = row0 + g * 4 + j;
        float ps = acc[j] * av_s, pd = acc[j] * av_d;
        #pragma unroll
        for (int mask = 16; mask >= 1; mask >>= 1) {
            ps += __shfl_xor(ps, mask);
            pd += __shfl_xor(pd, mask);
        }
        if (row < N_NODES) {
            h2[(size_t)row * 32 + c] = acc[j];
            if (c == 0) { s2s[row] = ps; s2d[row] = pd; }
        }
    }
}

// ---------------- Layer 2 aggregation ----------------

__global__ __launch_bounds__(256) void agg2_k(
        const int* __restrict__ csr, const int* __restrict__ offs,
        const float* __restrict__ h2, const float* __restrict__ s2s,
        const float* __restrict__ s2d, const float* __restrict__ b2,
        float* __restrict__ out) {
    int n = blockIdx.x * 8 + (threadIdx.x >> 5);
    int c = threadIdx.x & 31;
    if (n >= N_NODES) return;
    int beg = offs[n], end = offs[n + 1];
    float sd = s2d[n];
    float m = -3.4e38f, denom = 0.f, acc = 0.f;
    for (int i = beg; i < end; i++) {
        int s = csr[i];
        float e = s2s[s] + sd;
        e = (e >= 0.f) ? e : 0.2f * e;
        float mn = fmaxf(m, e);
        float scale = __expf(m - mn);
        float p = __expf(e - mn);
        float hv = h2[(size_t)s * 32 + c];
        denom = denom * scale + p;
        acc = acc * scale + p * hv;
        m = mn;
    }
    out[(size_t)n * 32 + c] = acc / (denom + 1e-16f) + b2[c];
}

// ---------------- launch ----------------

extern "C" void kernel_launch(void* const* d_in, const int* in_sizes, int n_in,
                              void* d_out, int out_size, void* d_ws, size_t ws_size,
                              hipStream_t stream) {
    const float* x   = (const float*)d_in[0];
    const int*   ei  = (const int*)d_in[1];
    const float* W1  = (const float*)d_in[2];
    const float* a1s = (const float*)d_in[3];
    const float* a1d = (const float*)d_in[4];
    const float* b1  = (const float*)d_in[5];
    const float* W2  = (const float*)d_in[6];
    const float* a2s = (const float*)d_in[7];
    const float* a2d = (const float*)d_in[8];
    const float* b2  = (const float*)d_in[9];
    float* out = (float*)d_out;

    char* w = (char*)d_ws;
    float* h1  = (float*)w; w += (size_t)N_NODES * 256 * 4;
    float* hr  = (float*)w; w += (size_t)N_NODES * 256 * 4;
    float* h2  = (float*)w; w += (size_t)N_NODES * 32 * 4;
    float* s1s = (float*)w; w += (size_t)N_NODES * 8 * 4;
    float* s1d = (float*)w; w += (size_t)N_NODES * 8 * 4;
    float* s2s = (float*)w; w += (size_t)N_NODES * 4;
    float* s2d = (float*)w; w += (size_t)N_NODES * 4;
    int* cnt    = (int*)w; w += (size_t)N_NODES * 4;
    int* offs   = (int*)w; w += (size_t)(N_NODES + 1) * 4;
    int* cursor = (int*)w; w += (size_t)(N_NODES + 4) * 4;   // keep 16B alignment
    int* csr    = (int*)w; w += (size_t)E_TOT * 4;

    hipMemsetAsync(cnt, 0, (size_t)N_NODES * 4, stream);
    hist_k<<<(E_TOT + 255) / 256, 256, 0, stream>>>(ei, cnt);
    scan_k<<<1, 1024, 0, stream>>>(cnt, offs, cursor);
    scat_k<<<(E_TOT + 255) / 256, 256, 0, stream>>>(ei, cursor, csr);

    gemm1_k<<<(N_NODES + 31) / 32, 256, 0, stream>>>(x, W1, a1s, a1d, h1, s1s, s1d);
    agg1_k<<<N_NODES, 256, 0, stream>>>(csr, offs, h1, s1s, s1d, b1, hr);
    gemm2_k<<<(N_NODES + 31) / 32, 256, 0, stream>>>(hr, W2, a2s, a2d, h2, s2s, s2d);
    agg2_k<<<(N_NODES + 7) / 8, 256, 0, stream>>>(csr, offs, h2, s2s, s2d, b2, out);
}

// Round 2
// 470.971 us; speedup vs baseline: 1.1067x; 1.1067x over previous
//
#include <hip/hip_runtime.h>
#include <math.h>

#define N_NODES 50000
#define N_EDGES 800000
#define E_TOT (N_EDGES + N_NODES)

// ---------------- CSR build ----------------

__global__ void hist_k(const int* __restrict__ ei, int* __restrict__ cnt) {
    int e = blockIdx.x * blockDim.x + threadIdx.x;
    if (e < N_EDGES)      atomicAdd(&cnt[ei[N_EDGES + e]], 1);   // dst row of edge_index
    else if (e < E_TOT)   atomicAdd(&cnt[e - N_EDGES], 1);        // self loop
}

__global__ void scan_k(const int* __restrict__ cnt, int* __restrict__ offs,
                       int* __restrict__ cursor) {
    __shared__ int wsum[16];
    __shared__ int carry;
    int tid = threadIdx.x;
    if (tid == 0) { carry = 0; offs[0] = 0; cursor[0] = 0; }
    for (int base = 0; base < N_NODES; base += 1024) {
        __syncthreads();
        int i = base + tid;
        int v = (i < N_NODES) ? cnt[i] : 0;
        int lane = tid & 63, w = tid >> 6;
        int x = v;
        #pragma unroll
        for (int d = 1; d < 64; d <<= 1) {
            int y = __shfl_up(x, d);
            if (lane >= d) x += y;
        }
        if (lane == 63) wsum[w] = x;
        __syncthreads();
        if (tid == 0) {
            int s = 0;
            #pragma unroll
            for (int j = 0; j < 16; j++) { s += wsum[j]; wsum[j] = s; }
        }
        __syncthreads();
        int excl = carry + (w ? wsum[w - 1] : 0);
        if (i < N_NODES) { offs[i + 1] = excl + x; cursor[i + 1] = excl + x; }
        __syncthreads();
        if (tid == 0) carry += wsum[15];
    }
}

__global__ void scat_k(const int* __restrict__ ei, int* __restrict__ cursor,
                       int* __restrict__ csr) {
    int e = blockIdx.x * blockDim.x + threadIdx.x;
    int s, d;
    if (e < N_EDGES)      { s = ei[e]; d = ei[N_EDGES + e]; }
    else if (e < E_TOT)   { s = e - N_EDGES; d = s; }
    else return;
    int p = atomicAdd(&cursor[d], 1);
    csr[p] = s;
}

// ---------------- Layer 1 GEMM + fused attention scores ----------------

__global__ __launch_bounds__(256) void gemm1_k(
        const float* __restrict__ x, const float* __restrict__ W1,
        const float* __restrict__ a1s, const float* __restrict__ a1d,
        float* __restrict__ h1, float* __restrict__ s1s, float* __restrict__ s1d) {
    __shared__ float xs[32][128];
    int tid = threadIdx.x;
    int row0 = blockIdx.x * 32;
    for (int i = tid; i < 32 * 32; i += 256) {
        int r = i >> 5, q = i & 31;
        int row = row0 + r; if (row >= N_NODES) row = N_NODES - 1;
        float4 v = ((const float4*)(x + (size_t)row * 128))[q];
        *((float4*)&xs[r][q * 4]) = v;
    }
    __syncthreads();
    float acc[32];
    #pragma unroll
    for (int r = 0; r < 32; r++) acc[r] = 0.f;
    int c = tid;
    for (int k = 0; k < 128; k += 4) {
        float w0 = W1[(k + 0) * 256 + c];
        float w1 = W1[(k + 1) * 256 + c];
        float w2 = W1[(k + 2) * 256 + c];
        float w3 = W1[(k + 3) * 256 + c];
        #pragma unroll
        for (int r = 0; r < 32; r++) {
            float4 xv = *((const float4*)&xs[r][k]);
            acc[r] = fmaf(xv.x, w0, acc[r]);
            acc[r] = fmaf(xv.y, w1, acc[r]);
            acc[r] = fmaf(xv.z, w2, acc[r]);
            acc[r] = fmaf(xv.w, w3, acc[r]);
        }
    }
    float as = a1s[c], ad = a1d[c];
    int hh = tid >> 5;
    #pragma unroll 4
    for (int r = 0; r < 32; r++) {
        int row = row0 + r;
        float ps = acc[r] * as, pd = acc[r] * ad;
        #pragma unroll
        for (int mask = 16; mask >= 1; mask >>= 1) {
            ps += __shfl_xor(ps, mask);
            pd += __shfl_xor(pd, mask);
        }
        if (row < N_NODES) {
            h1[(size_t)row * 256 + c] = acc[r];
            if ((tid & 31) == 0) {
                s1s[row * 8 + hh] = ps;
                s1d[row * 8 + hh] = pd;
            }
        }
    }
}

// ---------------- Layer 1 softmax stats + alpha materialization ----------------
// One wave per node: lane = e8*8 + h  (8 edges x 8 heads per tile)

__global__ __launch_bounds__(256) void stats1_k(
        const int* __restrict__ csr, const int* __restrict__ offs,
        const float* __restrict__ s1s, const float* __restrict__ s1d,
        float* __restrict__ alpha) {
    int n = blockIdx.x * 4 + (threadIdx.x >> 6);
    if (n >= N_NODES) return;
    int lane = threadIdx.x & 63;
    int e8 = lane >> 3, h = lane & 7;
    int beg = offs[n], end = offs[n + 1];
    float sd = s1d[n * 8 + h];
    float m = -3.4e38f, d = 0.f;
    for (int i = beg + e8; i < end; i += 8) {
        int s = csr[i];
        float e = s1s[s * 8 + h] + sd;
        e = (e >= 0.f) ? e : 0.2f * e;
        float mn = fmaxf(m, e);
        d = d * __expf(m - mn) + __expf(e - mn);
        m = mn;
    }
    #pragma unroll
    for (int mask = 8; mask <= 32; mask <<= 1) {   // butterfly over e8 bits
        float om = __shfl_xor(m, mask);
        float od = __shfl_xor(d, mask);
        float nm = fmaxf(m, om);
        d = d * __expf(m - nm) + od * __expf(om - nm);
        m = nm;
    }
    float inv = 1.f / (d + 1e-16f);
    for (int i = beg + e8; i < end; i += 8) {
        int s = csr[i];
        float e = s1s[s * 8 + h] + sd;
        e = (e >= 0.f) ? e : 0.2f * e;
        alpha[(size_t)i * 8 + h] = __expf(e - m) * inv;
    }
}

// ---------------- Layer 1 aggregation: pure weighted gather ----------------

__global__ __launch_bounds__(256) void agg1_k(
        const int* __restrict__ csr, const int* __restrict__ offs,
        const float* __restrict__ h1, const float* __restrict__ alpha,
        const float* __restrict__ b1, float* __restrict__ hr) {
    int n = blockIdx.x;
    int tid = threadIdx.x, h = tid >> 5;
    int beg = offs[n], end = offs[n + 1];
    float acc = 0.f;
    int i = beg;
    for (; i + 1 < end; i += 2) {
        int s0 = csr[i], s1 = csr[i + 1];
        float a0 = alpha[(size_t)i * 8 + h];
        float a1v = alpha[(size_t)(i + 1) * 8 + h];
        float v0 = h1[(size_t)s0 * 256 + tid];
        float v1 = h1[(size_t)s1 * 256 + tid];
        acc = fmaf(a0, v0, acc);
        acc = fmaf(a1v, v1, acc);
    }
    if (i < end) {
        int s0 = csr[i];
        acc = fmaf(alpha[(size_t)i * 8 + h], h1[(size_t)s0 * 256 + tid], acc);
    }
    float v = acc + b1[tid];
    hr[(size_t)n * 256 + tid] = fmaxf(v, 0.f);   // ReLU between layers
}

// ---------------- Layer 2 GEMM + fused scores ----------------

__global__ __launch_bounds__(256) void gemm2_k(
        const float* __restrict__ hr, const float* __restrict__ W2,
        const float* __restrict__ a2s, const float* __restrict__ a2d,
        float* __restrict__ h2, float* __restrict__ s2s, float* __restrict__ s2d) {
    __shared__ float hs[32][256];
    int tid = threadIdx.x;
    int row0 = blockIdx.x * 32;
    for (int i = tid; i < 32 * 64; i += 256) {
        int r = i >> 6, q = i & 63;
        int row = row0 + r; if (row >= N_NODES) row = N_NODES - 1;
        float4 v = ((const float4*)(hr + (size_t)row * 256))[q];
        *((float4*)&hs[r][q * 4]) = v;
    }
    __syncthreads();
    int c = tid & 31, g = tid >> 5;
    float acc[4] = {0.f, 0.f, 0.f, 0.f};
    for (int k = 0; k < 256; k++) {
        float wv = W2[k * 32 + c];
        #pragma unroll
        for (int j = 0; j < 4; j++) acc[j] += hs[g * 4 + j][k] * wv;
    }
    float av_s = a2s[c], av_d = a2d[c];
    #pragma unroll
    for (int j = 0; j < 4; j++) {
        int row = row0 + g * 4 + j;
        float ps = acc[j] * av_s, pd = acc[j] * av_d;
        #pragma unroll
        for (int mask = 16; mask >= 1; mask >>= 1) {
            ps += __shfl_xor(ps, mask);
            pd += __shfl_xor(pd, mask);
        }
        if (row < N_NODES) {
            h2[(size_t)row * 32 + c] = acc[j];
            if (c == 0) { s2s[row] = ps; s2d[row] = pd; }
        }
    }
}

// ---------------- Layer 2 softmax stats + alpha ----------------
// One wave per node, 64 edges in parallel, single head.

__global__ __launch_bounds__(256) void stats2_k(
        const int* __restrict__ csr, const int* __restrict__ offs,
        const float* __restrict__ s2s, const float* __restrict__ s2d,
        float* __restrict__ alpha2) {
    int n = blockIdx.x * 4 + (threadIdx.x >> 6);
    if (n >= N_NODES) return;
    int lane = threadIdx.x & 63;
    int beg = offs[n], end = offs[n + 1];
    float sd = s2d[n];
    float m = -3.4e38f, d = 0.f;
    for (int i = beg + lane; i < end; i += 64) {
        int s = csr[i];
        float e = s2s[s] + sd;
        e = (e >= 0.f) ? e : 0.2f * e;
        float mn = fmaxf(m, e);
        d = d * __expf(m - mn) + __expf(e - mn);
        m = mn;
    }
    #pragma unroll
    for (int mask = 1; mask <= 32; mask <<= 1) {
        float om = __shfl_xor(m, mask);
        float od = __shfl_xor(d, mask);
        float nm = fmaxf(m, om);
        d = d * __expf(m - nm) + od * __expf(om - nm);
        m = nm;
    }
    float inv = 1.f / (d + 1e-16f);
    for (int i = beg + lane; i < end; i += 64) {
        int s = csr[i];
        float e = s2s[s] + sd;
        e = (e >= 0.f) ? e : 0.2f * e;
        alpha2[i] = __expf(e - m) * inv;
    }
}

// ---------------- Layer 2 aggregation ----------------

__global__ __launch_bounds__(256) void agg2_k(
        const int* __restrict__ csr, const int* __restrict__ offs,
        const float* __restrict__ h2, const float* __restrict__ alpha2,
        const float* __restrict__ b2, float* __restrict__ out) {
    int n = blockIdx.x * 8 + (threadIdx.x >> 5);
    int c = threadIdx.x & 31;
    if (n >= N_NODES) return;
    int beg = offs[n], end = offs[n + 1];
    float acc = 0.f;
    int i = beg;
    for (; i + 1 < end; i += 2) {
        int s0 = csr[i], s1 = csr[i + 1];
        float a0 = alpha2[i], a1v = alpha2[i + 1];
        acc = fmaf(a0, h2[(size_t)s0 * 32 + c], acc);
        acc = fmaf(a1v, h2[(size_t)s1 * 32 + c], acc);
    }
    if (i < end) acc = fmaf(alpha2[i], h2[(size_t)csr[i] * 32 + c], acc);
    out[(size_t)n * 32 + c] = acc + b2[c];
}

// ---------------- launch ----------------

extern "C" void kernel_launch(void* const* d_in, const int* in_sizes, int n_in,
                              void* d_out, int out_size, void* d_ws, size_t ws_size,
                              hipStream_t stream) {
    const float* x   = (const float*)d_in[0];
    const int*   ei  = (const int*)d_in[1];
    const float* W1  = (const float*)d_in[2];
    const float* a1s = (const float*)d_in[3];
    const float* a1d = (const float*)d_in[4];
    const float* b1  = (const float*)d_in[5];
    const float* W2  = (const float*)d_in[6];
    const float* a2s = (const float*)d_in[7];
    const float* a2d = (const float*)d_in[8];
    const float* b2  = (const float*)d_in[9];
    float* out = (float*)d_out;

    char* w = (char*)d_ws;
    float* h1     = (float*)w; w += (size_t)N_NODES * 256 * 4;
    float* hr     = (float*)w; w += (size_t)N_NODES * 256 * 4;
    float* h2     = (float*)w; w += (size_t)N_NODES * 32 * 4;
    float* s1s    = (float*)w; w += (size_t)N_NODES * 8 * 4;
    float* s1d    = (float*)w; w += (size_t)N_NODES * 8 * 4;
    float* s2s    = (float*)w; w += (size_t)N_NODES * 4;
    float* s2d    = (float*)w; w += (size_t)N_NODES * 4;
    float* alpha  = (float*)w; w += (size_t)E_TOT * 8 * 4;
    float* alpha2 = (float*)w; w += (size_t)E_TOT * 4;
    int* cnt    = (int*)w; w += (size_t)N_NODES * 4;
    int* offs   = (int*)w; w += (size_t)(N_NODES + 1) * 4;
    int* cursor = (int*)w; w += (size_t)(N_NODES + 4) * 4;   // keep 16B alignment
    int* csr    = (int*)w; w += (size_t)E_TOT * 4;

    hipMemsetAsync(cnt, 0, (size_t)N_NODES * 4, stream);
    hist_k<<<(E_TOT + 255) / 256, 256, 0, stream>>>(ei, cnt);
    scan_k<<<1, 1024, 0, stream>>>(cnt, offs, cursor);
    scat_k<<<(E_TOT + 255) / 256, 256, 0, stream>>>(ei, cursor, csr);

    gemm1_k<<<(N_NODES + 31) / 32, 256, 0, stream>>>(x, W1, a1s, a1d, h1, s1s, s1d);
    stats1_k<<<(N_NODES + 3) / 4, 256, 0, stream>>>(csr, offs, s1s, s1d, alpha);
    agg1_k<<<N_NODES, 256, 0, stream>>>(csr, offs, h1, alpha, b1, hr);
    gemm2_k<<<(N_NODES + 31) / 32, 256, 0, stream>>>(hr, W2, a2s, a2d, h2, s2s, s2d);
    stats2_k<<<(N_NODES + 3) / 4, 256, 0, stream>>>(csr, offs, s2s, s2d, alpha2);
    agg2_k<<<(N_NODES + 7) / 8, 256, 0, stream>>>(csr, offs, h2, alpha2, b2, out);
}

// Round 3
// 400.955 us; speedup vs baseline: 1.3000x; 1.1746x over previous
//
#include <hip/hip_runtime.h>
#include <hip/hip_bf16.h>
#include <math.h>

#define N_NODES 50000
#define N_EDGES 800000
#define E_TOT (N_EDGES + N_NODES)
#define NB_SCAN ((N_NODES + 255) / 256)

// ---------------- CSR build ----------------

__global__ void hist_k(const int* __restrict__ ei, int* __restrict__ cnt) {
    int e = blockIdx.x * blockDim.x + threadIdx.x;
    if (e < N_EDGES)      atomicAdd(&cnt[ei[N_EDGES + e]], 1);   // dst row of edge_index
    else if (e < E_TOT)   atomicAdd(&cnt[e - N_EDGES], 1);        // self loop
}

// hierarchical scan: A) per-block inclusive scan, B) scan of block sums, C) add-back
__global__ __launch_bounds__(256) void scanA_k(const int* __restrict__ cnt,
                                               int* __restrict__ offs,
                                               int* __restrict__ bsum) {
    __shared__ int ws[4];
    int b = blockIdx.x, tid = threadIdx.x;
    int i = b * 256 + tid;
    int v = (i < N_NODES) ? cnt[i] : 0;
    int lane = tid & 63, w = tid >> 6;
    int x = v;
    #pragma unroll
    for (int d = 1; d < 64; d <<= 1) {
        int y = __shfl_up(x, d);
        if (lane >= d) x += y;
    }
    if (lane == 63) ws[w] = x;
    __syncthreads();
    if (tid == 0) {
        int s = 0;
        #pragma unroll
        for (int j = 0; j < 4; j++) { s += ws[j]; ws[j] = s; }
    }
    __syncthreads();
    int incl = x + (w ? ws[w - 1] : 0);
    if (i < N_NODES) offs[i + 1] = incl;          // within-block inclusive (partial)
    if (tid == 255) bsum[b] = incl;
}

__global__ __launch_bounds__(256) void scanB_k(const int* __restrict__ bsum,
                                               int* __restrict__ boffs) {
    __shared__ int ws[4];
    int tid = threadIdx.x;
    int v = (tid < NB_SCAN) ? bsum[tid] : 0;
    int lane = tid & 63, w = tid >> 6;
    int x = v;
    #pragma unroll
    for (int d = 1; d < 64; d <<= 1) {
        int y = __shfl_up(x, d);
        if (lane >= d) x += y;
    }
    if (lane == 63) ws[w] = x;
    __syncthreads();
    if (tid == 0) {
        int s = 0;
        #pragma unroll
        for (int j = 0; j < 4; j++) { s += ws[j]; ws[j] = s; }
    }
    __syncthreads();
    int incl = x + (w ? ws[w - 1] : 0);
    if (tid < NB_SCAN) boffs[tid] = incl - v;     // exclusive block prefix
}

__global__ __launch_bounds__(256) void scanC_k(const int* __restrict__ boffs,
                                               int* __restrict__ offs,
                                               int* __restrict__ cursor) {
    int b = blockIdx.x;
    int i = b * 256 + threadIdx.x;
    if (i == 0) { offs[0] = 0; cursor[0] = 0; }
    if (i < N_NODES) {
        int v = offs[i + 1] + boffs[b];
        offs[i + 1] = v;
        cursor[i + 1] = v;
    }
}

__global__ void scat_k(const int* __restrict__ ei, int* __restrict__ cursor,
                       int* __restrict__ csr) {
    int e = blockIdx.x * blockDim.x + threadIdx.x;
    int s, d;
    if (e < N_EDGES)      { s = ei[e]; d = ei[N_EDGES + e]; }
    else if (e < E_TOT)   { s = e - N_EDGES; d = s; }
    else return;
    int p = atomicAdd(&cursor[d], 1);
    csr[p] = s;
}

// ---------------- Layer 1 GEMM + fused attention scores ----------------
// h1b (bf16) [N,256]; scores from f32 accumulators.

__global__ __launch_bounds__(256) void gemm1_k(
        const float* __restrict__ x, const float* __restrict__ W1,
        const float* __restrict__ a1s, const float* __restrict__ a1d,
        __hip_bfloat16* __restrict__ h1b, float* __restrict__ s1s,
        float* __restrict__ s1d) {
    __shared__ float xs[32][128];
    int tid = threadIdx.x;
    int row0 = blockIdx.x * 32;
    for (int i = tid; i < 32 * 32; i += 256) {
        int r = i >> 5, q = i & 31;
        int row = row0 + r; if (row >= N_NODES) row = N_NODES - 1;
        float4 v = ((const float4*)(x + (size_t)row * 128))[q];
        *((float4*)&xs[r][q * 4]) = v;
    }
    __syncthreads();
    float acc[32];
    #pragma unroll
    for (int r = 0; r < 32; r++) acc[r] = 0.f;
    int c = tid;
    for (int k = 0; k < 128; k += 4) {
        float w0 = W1[(k + 0) * 256 + c];
        float w1 = W1[(k + 1) * 256 + c];
        float w2 = W1[(k + 2) * 256 + c];
        float w3 = W1[(k + 3) * 256 + c];
        #pragma unroll
        for (int r = 0; r < 32; r++) {
            float4 xv = *((const float4*)&xs[r][k]);
            acc[r] = fmaf(xv.x, w0, acc[r]);
            acc[r] = fmaf(xv.y, w1, acc[r]);
            acc[r] = fmaf(xv.z, w2, acc[r]);
            acc[r] = fmaf(xv.w, w3, acc[r]);
        }
    }
    float as = a1s[c], ad = a1d[c];
    int hh = tid >> 5;
    #pragma unroll 4
    for (int r = 0; r < 32; r++) {
        int row = row0 + r;
        float ps = acc[r] * as, pd = acc[r] * ad;
        #pragma unroll
        for (int mask = 16; mask >= 1; mask >>= 1) {
            ps += __shfl_xor(ps, mask);
            pd += __shfl_xor(pd, mask);
        }
        if (row < N_NODES) {
            h1b[(size_t)row * 256 + c] = __float2bfloat16(acc[r]);
            if ((tid & 31) == 0) {
                s1s[row * 8 + hh] = ps;
                s1d[row * 8 + hh] = pd;
            }
        }
    }
}

// ---------------- Layer 1 softmax stats + alpha materialization ----------------

__global__ __launch_bounds__(256) void stats1_k(
        const int* __restrict__ csr, const int* __restrict__ offs,
        const float* __restrict__ s1s, const float* __restrict__ s1d,
        float* __restrict__ alpha) {
    int n = blockIdx.x * 4 + (threadIdx.x >> 6);
    if (n >= N_NODES) return;
    int lane = threadIdx.x & 63;
    int e8 = lane >> 3, h = lane & 7;
    int beg = offs[n], end = offs[n + 1];
    float sd = s1d[n * 8 + h];
    float m = -3.4e38f, d = 0.f;
    for (int i = beg + e8; i < end; i += 8) {
        int s = csr[i];
        float e = s1s[s * 8 + h] + sd;
        e = (e >= 0.f) ? e : 0.2f * e;
        float mn = fmaxf(m, e);
        d = d * __expf(m - mn) + __expf(e - mn);
        m = mn;
    }
    #pragma unroll
    for (int mask = 8; mask <= 32; mask <<= 1) {
        float om = __shfl_xor(m, mask);
        float od = __shfl_xor(d, mask);
        float nm = fmaxf(m, om);
        d = d * __expf(m - nm) + od * __expf(om - nm);
        m = nm;
    }
    float inv = 1.f / (d + 1e-16f);
    for (int i = beg + e8; i < end; i += 8) {
        int s = csr[i];
        float e = s1s[s * 8 + h] + sd;
        e = (e >= 0.f) ? e : 0.2f * e;
        alpha[(size_t)i * 8 + h] = __expf(e - m) * inv;
    }
}

// ---------------- Layer 1 aggregation: bf16x2 weighted gather ----------------
// 2 nodes / block, 128 threads / node, 2 channels / thread.

__global__ __launch_bounds__(256) void agg1_k(
        const int* __restrict__ csr, const int* __restrict__ offs,
        const __hip_bfloat16* __restrict__ h1b, const float* __restrict__ alpha,
        const float* __restrict__ b1, float* __restrict__ hr) {
    int t = threadIdx.x & 127;
    int n = blockIdx.x * 2 + (threadIdx.x >> 7);
    int h = t >> 4;                       // head of channels {2t, 2t+1}
    int beg = offs[n], end = offs[n + 1];
    const __hip_bfloat162* h2v = (const __hip_bfloat162*)h1b;
    float acc0 = 0.f, acc1 = 0.f;
    int i = beg;
    for (; i + 1 < end; i += 2) {
        int s0 = csr[i], s1 = csr[i + 1];
        float a0 = alpha[(size_t)i * 8 + h];
        float a1v = alpha[(size_t)(i + 1) * 8 + h];
        __hip_bfloat162 v0 = h2v[(size_t)s0 * 128 + t];
        __hip_bfloat162 v1 = h2v[(size_t)s1 * 128 + t];
        acc0 = fmaf(a0, __bfloat162float(v0.x), acc0);
        acc1 = fmaf(a0, __bfloat162float(v0.y), acc1);
        acc0 = fmaf(a1v, __bfloat162float(v1.x), acc0);
        acc1 = fmaf(a1v, __bfloat162float(v1.y), acc1);
    }
    if (i < end) {
        int s0 = csr[i];
        float a0 = alpha[(size_t)i * 8 + h];
        __hip_bfloat162 v0 = h2v[(size_t)s0 * 128 + t];
        acc0 = fmaf(a0, __bfloat162float(v0.x), acc0);
        acc1 = fmaf(a0, __bfloat162float(v0.y), acc1);
    }
    int c0 = 2 * t;
    float2 o;
    o.x = fmaxf(acc0 + b1[c0], 0.f);
    o.y = fmaxf(acc1 + b1[c0 + 1], 0.f);
    ((float2*)hr)[(size_t)n * 128 + t] = o;      // ReLU between layers
}

// ---------------- Layer 2 GEMM + fused scores ----------------

__global__ __launch_bounds__(256) void gemm2_k(
        const float* __restrict__ hr, const float* __restrict__ W2,
        const float* __restrict__ a2s, const float* __restrict__ a2d,
        __hip_bfloat16* __restrict__ h2b, float* __restrict__ s2s,
        float* __restrict__ s2d) {
    __shared__ float hs[32][256];
    int tid = threadIdx.x;
    int row0 = blockIdx.x * 32;
    for (int i = tid; i < 32 * 64; i += 256) {
        int r = i >> 6, q = i & 63;
        int row = row0 + r; if (row >= N_NODES) row = N_NODES - 1;
        float4 v = ((const float4*)(hr + (size_t)row * 256))[q];
        *((float4*)&hs[r][q * 4]) = v;
    }
    __syncthreads();
    int c = tid & 31, g = tid >> 5;
    float acc[4] = {0.f, 0.f, 0.f, 0.f};
    for (int k = 0; k < 256; k++) {
        float wv = W2[k * 32 + c];
        #pragma unroll
        for (int j = 0; j < 4; j++) acc[j] += hs[g * 4 + j][k] * wv;
    }
    float av_s = a2s[c], av_d = a2d[c];
    #pragma unroll
    for (int j = 0; j < 4; j++) {
        int row = row0 + g * 4 + j;
        float ps = acc[j] * av_s, pd = acc[j] * av_d;
        #pragma unroll
        for (int mask = 16; mask >= 1; mask >>= 1) {
            ps += __shfl_xor(ps, mask);
            pd += __shfl_xor(pd, mask);
        }
        if (row < N_NODES) {
            h2b[(size_t)row * 32 + c] = __float2bfloat16(acc[j]);
            if (c == 0) { s2s[row] = ps; s2d[row] = pd; }
        }
    }
}

// ---------------- Layer 2 softmax stats + alpha ----------------

__global__ __launch_bounds__(256) void stats2_k(
        const int* __restrict__ csr, const int* __restrict__ offs,
        const float* __restrict__ s2s, const float* __restrict__ s2d,
        float* __restrict__ alpha2) {
    int n = blockIdx.x * 4 + (threadIdx.x >> 6);
    if (n >= N_NODES) return;
    int lane = threadIdx.x & 63;
    int beg = offs[n], end = offs[n + 1];
    float sd = s2d[n];
    float m = -3.4e38f, d = 0.f;
    for (int i = beg + lane; i < end; i += 64) {
        int s = csr[i];
        float e = s2s[s] + sd;
        e = (e >= 0.f) ? e : 0.2f * e;
        float mn = fmaxf(m, e);
        d = d * __expf(m - mn) + __expf(e - mn);
        m = mn;
    }
    #pragma unroll
    for (int mask = 1; mask <= 32; mask <<= 1) {
        float om = __shfl_xor(m, mask);
        float od = __shfl_xor(d, mask);
        float nm = fmaxf(m, om);
        d = d * __expf(m - nm) + od * __expf(om - nm);
        m = nm;
    }
    float inv = 1.f / (d + 1e-16f);
    for (int i = beg + lane; i < end; i += 64) {
        int s = csr[i];
        float e = s2s[s] + sd;
        e = (e >= 0.f) ? e : 0.2f * e;
        alpha2[i] = __expf(e - m) * inv;
    }
}

// ---------------- Layer 2 aggregation ----------------

__global__ __launch_bounds__(256) void agg2_k(
        const int* __restrict__ csr, const int* __restrict__ offs,
        const __hip_bfloat16* __restrict__ h2b, const float* __restrict__ alpha2,
        const float* __restrict__ b2, float* __restrict__ out) {
    int n = blockIdx.x * 8 + (threadIdx.x >> 5);
    int c = threadIdx.x & 31;
    if (n >= N_NODES) return;
    int beg = offs[n], end = offs[n + 1];
    float acc = 0.f;
    int i = beg;
    for (; i + 1 < end; i += 2) {
        int s0 = csr[i], s1 = csr[i + 1];
        float a0 = alpha2[i], a1v = alpha2[i + 1];
        acc = fmaf(a0, __bfloat162float(h2b[(size_t)s0 * 32 + c]), acc);
        acc = fmaf(a1v, __bfloat162float(h2b[(size_t)s1 * 32 + c]), acc);
    }
    if (i < end)
        acc = fmaf(alpha2[i], __bfloat162float(h2b[(size_t)csr[i] * 32 + c]), acc);
    out[(size_t)n * 32 + c] = acc + b2[c];
}

// ---------------- launch ----------------

extern "C" void kernel_launch(void* const* d_in, const int* in_sizes, int n_in,
                              void* d_out, int out_size, void* d_ws, size_t ws_size,
                              hipStream_t stream) {
    const float* x   = (const float*)d_in[0];
    const int*   ei  = (const int*)d_in[1];
    const float* W1  = (const float*)d_in[2];
    const float* a1s = (const float*)d_in[3];
    const float* a1d = (const float*)d_in[4];
    const float* b1  = (const float*)d_in[5];
    const float* W2  = (const float*)d_in[6];
    const float* a2s = (const float*)d_in[7];
    const float* a2d = (const float*)d_in[8];
    const float* b2  = (const float*)d_in[9];
    float* out = (float*)d_out;

    char* w = (char*)d_ws;
    float* hr     = (float*)w; w += (size_t)N_NODES * 256 * 4;
    __hip_bfloat16* h1b = (__hip_bfloat16*)w; w += (size_t)N_NODES * 256 * 2;
    __hip_bfloat16* h2b = (__hip_bfloat16*)w; w += (size_t)N_NODES * 32 * 2;
    float* s1s    = (float*)w; w += (size_t)N_NODES * 8 * 4;
    float* s1d    = (float*)w; w += (size_t)N_NODES * 8 * 4;
    float* s2s    = (float*)w; w += (size_t)N_NODES * 4;
    float* s2d    = (float*)w; w += (size_t)N_NODES * 4;
    float* alpha  = (float*)w; w += (size_t)E_TOT * 8 * 4;
    float* alpha2 = (float*)w; w += (size_t)E_TOT * 4;
    int* cnt    = (int*)w; w += (size_t)N_NODES * 4;
    int* offs   = (int*)w; w += (size_t)(N_NODES + 1) * 4;
    int* cursor = (int*)w; w += (size_t)(N_NODES + 4) * 4;   // keep alignment
    int* bsum   = (int*)w; w += (size_t)NB_SCAN * 4;
    int* boffs  = (int*)w; w += (size_t)NB_SCAN * 4;
    int* csr    = (int*)w; w += (size_t)E_TOT * 4;

    hipMemsetAsync(cnt, 0, (size_t)N_NODES * 4, stream);
    hist_k<<<(E_TOT + 255) / 256, 256, 0, stream>>>(ei, cnt);
    scanA_k<<<NB_SCAN, 256, 0, stream>>>(cnt, offs, bsum);
    scanB_k<<<1, 256, 0, stream>>>(bsum, boffs);
    scanC_k<<<NB_SCAN, 256, 0, stream>>>(boffs, offs, cursor);
    scat_k<<<(E_TOT + 255) / 256, 256, 0, stream>>>(ei, cursor, csr);

    gemm1_k<<<(N_NODES + 31) / 32, 256, 0, stream>>>(x, W1, a1s, a1d, h1b, s1s, s1d);
    stats1_k<<<(N_NODES + 3) / 4, 256, 0, stream>>>(csr, offs, s1s, s1d, alpha);
    agg1_k<<<N_NODES / 2, 256, 0, stream>>>(csr, offs, h1b, alpha, b1, hr);
    gemm2_k<<<(N_NODES + 31) / 32, 256, 0, stream>>>(hr, W2, a2s, a2d, h2b, s2s, s2d);
    stats2_k<<<(N_NODES + 3) / 4, 256, 0, stream>>>(csr, offs, s2s, s2d, alpha2);
    agg2_k<<<(N_NODES + 7) / 8, 256, 0, stream>>>(csr, offs, h2b, alpha2, b2, out);
}

// Round 4
// 373.536 us; speedup vs baseline: 1.3954x; 1.0734x over previous
//
#include <hip/hip_runtime.h>
#include <math.h>

#define N_NODES 50000
#define N_EDGES 800000
#define E_TOT (N_EDGES + N_NODES)
#define NB_SCAN ((N_NODES + 255) / 256)

typedef unsigned int uint;
typedef unsigned short ushort;

__device__ __forceinline__ ushort f2bf(float f) {          // RNE f32->bf16
    uint u = __float_as_uint(f);
    return (ushort)((u + 0x7FFFu + ((u >> 16) & 1u)) >> 16);
}
__device__ __forceinline__ float bf2f(ushort u) {
    return __uint_as_float((uint)u << 16);
}

// ---------------- CSR build ----------------

__global__ void hist_k(const int* __restrict__ ei, int* __restrict__ cnt) {
    int e = blockIdx.x * blockDim.x + threadIdx.x;
    if (e < N_EDGES)      atomicAdd(&cnt[ei[N_EDGES + e]], 1);
    else if (e < E_TOT)   atomicAdd(&cnt[e - N_EDGES], 1);
}

__global__ __launch_bounds__(256) void scanA_k(const int* __restrict__ cnt,
                                               int* __restrict__ offs,
                                               int* __restrict__ bsum) {
    __shared__ int ws[4];
    int b = blockIdx.x, tid = threadIdx.x;
    int i = b * 256 + tid;
    int v = (i < N_NODES) ? cnt[i] : 0;
    int lane = tid & 63, w = tid >> 6;
    int x = v;
    #pragma unroll
    for (int d = 1; d < 64; d <<= 1) {
        int y = __shfl_up(x, d);
        if (lane >= d) x += y;
    }
    if (lane == 63) ws[w] = x;
    __syncthreads();
    if (tid == 0) {
        int s = 0;
        #pragma unroll
        for (int j = 0; j < 4; j++) { s += ws[j]; ws[j] = s; }
    }
    __syncthreads();
    int incl = x + (w ? ws[w - 1] : 0);
    if (i < N_NODES) offs[i + 1] = incl;
    if (tid == 255) bsum[b] = incl;
}

__global__ __launch_bounds__(256) void scanB_k(const int* __restrict__ bsum,
                                               int* __restrict__ boffs) {
    __shared__ int ws[4];
    int tid = threadIdx.x;
    int v = (tid < NB_SCAN) ? bsum[tid] : 0;
    int lane = tid & 63, w = tid >> 6;
    int x = v;
    #pragma unroll
    for (int d = 1; d < 64; d <<= 1) {
        int y = __shfl_up(x, d);
        if (lane >= d) x += y;
    }
    if (lane == 63) ws[w] = x;
    __syncthreads();
    if (tid == 0) {
        int s = 0;
        #pragma unroll
        for (int j = 0; j < 4; j++) { s += ws[j]; ws[j] = s; }
    }
    __syncthreads();
    int incl = x + (w ? ws[w - 1] : 0);
    if (tid < NB_SCAN) boffs[tid] = incl - v;
}

__global__ __launch_bounds__(256) void scanC_k(const int* __restrict__ boffs,
                                               int* __restrict__ offs,
                                               int* __restrict__ cursor) {
    int b = blockIdx.x;
    int i = b * 256 + threadIdx.x;
    if (i == 0) { offs[0] = 0; cursor[0] = 0; }
    if (i < N_NODES) {
        int v = offs[i + 1] + boffs[b];
        offs[i + 1] = v;
        cursor[i + 1] = v;
    }
}

__global__ void scat_k(const int* __restrict__ ei, int* __restrict__ cursor,
                       int* __restrict__ csr) {
    int e = blockIdx.x * blockDim.x + threadIdx.x;
    int s, d;
    if (e < N_EDGES)      { s = ei[e]; d = ei[N_EDGES + e]; }
    else if (e < E_TOT)   { s = e - N_EDGES; d = s; }
    else return;
    int p = atomicAdd(&cursor[d], 1);
    csr[p] = s;
}

// ---------------- Layer 1 GEMM (64x256 tile, 16x4 per thread, LDS broadcast) --

__global__ __launch_bounds__(256) void gemm1_k(
        const float* __restrict__ x, const float* __restrict__ W1,
        const float* __restrict__ a1s, const float* __restrict__ a1d,
        ushort* __restrict__ h1u, float* __restrict__ s1s,
        float* __restrict__ s1d) {
    __shared__ float xs[64][128];
    int tid = threadIdx.x;
    int row0 = blockIdx.x * 64;
    for (int i = tid; i < 64 * 32; i += 256) {
        int r = i >> 5, q = i & 31;
        int row = row0 + r; if (row >= N_NODES) row = N_NODES - 1;
        float4 v = ((const float4*)(x + (size_t)row * 128))[q];
        *((float4*)&xs[r][q * 4]) = v;
    }
    __syncthreads();
    int lane = tid & 63, wv = tid >> 6;
    int c0 = lane * 4;
    int rbase = wv * 16;
    float acc[16][4];
    #pragma unroll
    for (int r = 0; r < 16; r++)
        #pragma unroll
        for (int j = 0; j < 4; j++) acc[r][j] = 0.f;

    for (int k = 0; k < 128; k += 4) {
        float4 w0 = *((const float4*)(W1 + (size_t)(k + 0) * 256 + c0));
        float4 w1 = *((const float4*)(W1 + (size_t)(k + 1) * 256 + c0));
        float4 w2 = *((const float4*)(W1 + (size_t)(k + 2) * 256 + c0));
        float4 w3 = *((const float4*)(W1 + (size_t)(k + 3) * 256 + c0));
        #pragma unroll
        for (int r = 0; r < 16; r++) {
            float4 xv = *((const float4*)&xs[rbase + r][k]);   // broadcast read
            acc[r][0] = fmaf(xv.x, w0.x, acc[r][0]);
            acc[r][1] = fmaf(xv.x, w0.y, acc[r][1]);
            acc[r][2] = fmaf(xv.x, w0.z, acc[r][2]);
            acc[r][3] = fmaf(xv.x, w0.w, acc[r][3]);
            acc[r][0] = fmaf(xv.y, w1.x, acc[r][0]);
            acc[r][1] = fmaf(xv.y, w1.y, acc[r][1]);
            acc[r][2] = fmaf(xv.y, w1.z, acc[r][2]);
            acc[r][3] = fmaf(xv.y, w1.w, acc[r][3]);
            acc[r][0] = fmaf(xv.z, w2.x, acc[r][0]);
            acc[r][1] = fmaf(xv.z, w2.y, acc[r][1]);
            acc[r][2] = fmaf(xv.z, w2.z, acc[r][2]);
            acc[r][3] = fmaf(xv.z, w2.w, acc[r][3]);
            acc[r][0] = fmaf(xv.w, w3.x, acc[r][0]);
            acc[r][1] = fmaf(xv.w, w3.y, acc[r][1]);
            acc[r][2] = fmaf(xv.w, w3.z, acc[r][2]);
            acc[r][3] = fmaf(xv.w, w3.w, acc[r][3]);
        }
    }

    float as0 = a1s[c0], as1 = a1s[c0 + 1], as2 = a1s[c0 + 2], as3 = a1s[c0 + 3];
    float ad0 = a1d[c0], ad1 = a1d[c0 + 1], ad2 = a1d[c0 + 2], ad3 = a1d[c0 + 3];
    int h = lane >> 3;
    #pragma unroll 4
    for (int r = 0; r < 16; r++) {
        int row = row0 + rbase + r;
        float ps = acc[r][0] * as0 + acc[r][1] * as1 + acc[r][2] * as2 + acc[r][3] * as3;
        float pd = acc[r][0] * ad0 + acc[r][1] * ad1 + acc[r][2] * ad2 + acc[r][3] * ad3;
        #pragma unroll
        for (int mask = 1; mask <= 4; mask <<= 1) {
            ps += __shfl_xor(ps, mask);
            pd += __shfl_xor(pd, mask);
        }
        if (row < N_NODES) {
            uint lo = (uint)f2bf(acc[r][0]) | ((uint)f2bf(acc[r][1]) << 16);
            uint hi = (uint)f2bf(acc[r][2]) | ((uint)f2bf(acc[r][3]) << 16);
            *((uint2*)(h1u + (size_t)row * 256 + c0)) = make_uint2(lo, hi);
            if ((lane & 7) == 0) {
                s1s[row * 8 + h] = ps;
                s1d[row * 8 + h] = pd;
            }
        }
    }
}

// ---------------- Layer 1 softmax stats: (m, inv_denom) only ----------------

__global__ __launch_bounds__(256) void stats1_k(
        const int* __restrict__ csr, const int* __restrict__ offs,
        const float* __restrict__ s1s, const float* __restrict__ s1d,
        float2* __restrict__ minv) {
    int n = blockIdx.x * 4 + (threadIdx.x >> 6);
    if (n >= N_NODES) return;
    int lane = threadIdx.x & 63;
    int e8 = lane >> 3, h = lane & 7;
    int beg = offs[n], end = offs[n + 1];
    float sd = s1d[n * 8 + h];
    float m = -3.4e38f, d = 0.f;
    for (int i = beg + e8; i < end; i += 8) {
        int s = csr[i];
        float e = s1s[s * 8 + h] + sd;
        e = (e >= 0.f) ? e : 0.2f * e;
        float mn = fmaxf(m, e);
        d = d * __expf(m - mn) + __expf(e - mn);
        m = mn;
    }
    #pragma unroll
    for (int mask = 8; mask <= 32; mask <<= 1) {
        float om = __shfl_xor(m, mask);
        float od = __shfl_xor(d, mask);
        float nm = fmaxf(m, om);
        d = d * __expf(m - nm) + od * __expf(om - nm);
        m = nm;
    }
    if (e8 == 0) {
        float2 o; o.x = m; o.y = 1.f / (d + 1e-16f);
        minv[n * 8 + h] = o;
    }
}

// ---------------- Layer 1 aggregation: gather + on-the-fly alpha ----------------
// 2 nodes / block, 128 threads / node, 2 channels / thread.

__global__ __launch_bounds__(256) void agg1_k(
        const int* __restrict__ csr, const int* __restrict__ offs,
        const ushort* __restrict__ h1u, const float* __restrict__ s1s,
        const float* __restrict__ s1d, const float2* __restrict__ minv,
        const float* __restrict__ b1, float* __restrict__ hr) {
    int t = threadIdx.x & 127;
    int n = blockIdx.x * 2 + (threadIdx.x >> 7);
    int h = t >> 4;                        // head of channels {2t, 2t+1}
    int beg = offs[n], end = offs[n + 1];
    float sd = s1d[n * 8 + h];
    float2 mi = minv[n * 8 + h];
    float m = mi.x, inv = mi.y;
    const uint* h2v = (const uint*)h1u;
    float acc0 = 0.f, acc1 = 0.f;
    int i = beg;
    for (; i + 1 < end; i += 2) {
        int s0 = csr[i], s1 = csr[i + 1];
        float e0 = s1s[s0 * 8 + h] + sd;
        float e1 = s1s[s1 * 8 + h] + sd;
        e0 = (e0 >= 0.f) ? e0 : 0.2f * e0;
        e1 = (e1 >= 0.f) ? e1 : 0.2f * e1;
        float a0 = __expf(e0 - m) * inv;
        float a1v = __expf(e1 - m) * inv;
        uint v0 = h2v[(size_t)s0 * 128 + t];
        uint v1 = h2v[(size_t)s1 * 128 + t];
        acc0 = fmaf(a0, __uint_as_float(v0 << 16), acc0);
        acc1 = fmaf(a0, __uint_as_float(v0 & 0xFFFF0000u), acc1);
        acc0 = fmaf(a1v, __uint_as_float(v1 << 16), acc0);
        acc1 = fmaf(a1v, __uint_as_float(v1 & 0xFFFF0000u), acc1);
    }
    if (i < end) {
        int s0 = csr[i];
        float e0 = s1s[s0 * 8 + h] + sd;
        e0 = (e0 >= 0.f) ? e0 : 0.2f * e0;
        float a0 = __expf(e0 - m) * inv;
        uint v0 = h2v[(size_t)s0 * 128 + t];
        acc0 = fmaf(a0, __uint_as_float(v0 << 16), acc0);
        acc1 = fmaf(a0, __uint_as_float(v0 & 0xFFFF0000u), acc1);
    }
    int c0 = 2 * t;
    float2 o;
    o.x = fmaxf(acc0 + b1[c0], 0.f);
    o.y = fmaxf(acc1 + b1[c0 + 1], 0.f);
    ((float2*)hr)[(size_t)n * 128 + t] = o;
}

// ---------------- Layer 2 GEMM (32-row tile, 4x1 per thread, LDS broadcast) --

__global__ __launch_bounds__(256) void gemm2_k(
        const float* __restrict__ hr, const float* __restrict__ W2,
        const float* __restrict__ a2s, const float* __restrict__ a2d,
        ushort* __restrict__ h2u, float* __restrict__ s2s,
        float* __restrict__ s2d) {
    __shared__ float hs[32][256];
    int tid = threadIdx.x;
    int row0 = blockIdx.x * 32;
    for (int i = tid; i < 32 * 64; i += 256) {
        int r = i >> 6, q = i & 63;
        int row = row0 + r; if (row >= N_NODES) row = N_NODES - 1;
        float4 v = ((const float4*)(hr + (size_t)row * 256))[q];
        *((float4*)&hs[r][q * 4]) = v;
    }
    __syncthreads();
    int c = tid & 31, g = tid >> 5;       // rows g*4 .. g*4+3
    float acc[4] = {0.f, 0.f, 0.f, 0.f};
    for (int k = 0; k < 256; k += 4) {
        float w0 = W2[(size_t)(k + 0) * 32 + c];
        float w1 = W2[(size_t)(k + 1) * 32 + c];
        float w2 = W2[(size_t)(k + 2) * 32 + c];
        float w3 = W2[(size_t)(k + 3) * 32 + c];
        #pragma unroll
        for (int r = 0; r < 4; r++) {
            float4 xv = *((const float4*)&hs[g * 4 + r][k]);   // 2-way broadcast
            acc[r] = fmaf(xv.x, w0, acc[r]);
            acc[r] = fmaf(xv.y, w1, acc[r]);
            acc[r] = fmaf(xv.z, w2, acc[r]);
            acc[r] = fmaf(xv.w, w3, acc[r]);
        }
    }
    float av_s = a2s[c], av_d = a2d[c];
    #pragma unroll
    for (int r = 0; r < 4; r++) {
        int row = row0 + g * 4 + r;
        float ps = acc[r] * av_s, pd = acc[r] * av_d;
        #pragma unroll
        for (int mask = 16; mask >= 1; mask >>= 1) {
            ps += __shfl_xor(ps, mask);
            pd += __shfl_xor(pd, mask);
        }
        if (row < N_NODES) {
            h2u[(size_t)row * 32 + c] = f2bf(acc[r]);
            if (c == 0) { s2s[row] = ps; s2d[row] = pd; }
        }
    }
}

// ---------------- Layer 2 softmax stats + alpha ----------------

__global__ __launch_bounds__(256) void stats2_k(
        const int* __restrict__ csr, const int* __restrict__ offs,
        const float* __restrict__ s2s, const float* __restrict__ s2d,
        float* __restrict__ alpha2) {
    int n = blockIdx.x * 4 + (threadIdx.x >> 6);
    if (n >= N_NODES) return;
    int lane = threadIdx.x & 63;
    int beg = offs[n], end = offs[n + 1];
    float sd = s2d[n];
    float m = -3.4e38f, d = 0.f;
    for (int i = beg + lane; i < end; i += 64) {
        int s = csr[i];
        float e = s2s[s] + sd;
        e = (e >= 0.f) ? e : 0.2f * e;
        float mn = fmaxf(m, e);
        d = d * __expf(m - mn) + __expf(e - mn);
        m = mn;
    }
    #pragma unroll
    for (int mask = 1; mask <= 32; mask <<= 1) {
        float om = __shfl_xor(m, mask);
        float od = __shfl_xor(d, mask);
        float nm = fmaxf(m, om);
        d = d * __expf(m - nm) + od * __expf(om - nm);
        m = nm;
    }
    float inv = 1.f / (d + 1e-16f);
    for (int i = beg + lane; i < end; i += 64) {
        int s = csr[i];
        float e = s2s[s] + sd;
        e = (e >= 0.f) ? e : 0.2f * e;
        alpha2[i] = __expf(e - m) * inv;
    }
}

// ---------------- Layer 2 aggregation ----------------

__global__ __launch_bounds__(256) void agg2_k(
        const int* __restrict__ csr, const int* __restrict__ offs,
        const ushort* __restrict__ h2u, const float* __restrict__ alpha2,
        const float* __restrict__ b2, float* __restrict__ out) {
    int n = blockIdx.x * 8 + (threadIdx.x >> 5);
    int c = threadIdx.x & 31;
    if (n >= N_NODES) return;
    int beg = offs[n], end = offs[n + 1];
    float acc = 0.f;
    int i = beg;
    for (; i + 1 < end; i += 2) {
        int s0 = csr[i], s1 = csr[i + 1];
        float a0 = alpha2[i], a1v = alpha2[i + 1];
        acc = fmaf(a0, bf2f(h2u[(size_t)s0 * 32 + c]), acc);
        acc = fmaf(a1v, bf2f(h2u[(size_t)s1 * 32 + c]), acc);
    }
    if (i < end)
        acc = fmaf(alpha2[i], bf2f(h2u[(size_t)csr[i] * 32 + c]), acc);
    out[(size_t)n * 32 + c] = acc + b2[c];
}

// ---------------- launch ----------------

extern "C" void kernel_launch(void* const* d_in, const int* in_sizes, int n_in,
                              void* d_out, int out_size, void* d_ws, size_t ws_size,
                              hipStream_t stream) {
    const float* x   = (const float*)d_in[0];
    const int*   ei  = (const int*)d_in[1];
    const float* W1  = (const float*)d_in[2];
    const float* a1s = (const float*)d_in[3];
    const float* a1d = (const float*)d_in[4];
    const float* b1  = (const float*)d_in[5];
    const float* W2  = (const float*)d_in[6];
    const float* a2s = (const float*)d_in[7];
    const float* a2d = (const float*)d_in[8];
    const float* b2  = (const float*)d_in[9];
    float* out = (float*)d_out;

    char* w = (char*)d_ws;
    float* hr     = (float*)w;  w += (size_t)N_NODES * 256 * 4;
    ushort* h1u   = (ushort*)w; w += (size_t)N_NODES * 256 * 2;
    ushort* h2u   = (ushort*)w; w += (size_t)N_NODES * 32 * 2;
    float* s1s    = (float*)w;  w += (size_t)N_NODES * 8 * 4;
    float* s1d    = (float*)w;  w += (size_t)N_NODES * 8 * 4;
    float* s2s    = (float*)w;  w += (size_t)N_NODES * 4;
    float* s2d    = (float*)w;  w += (size_t)N_NODES * 4;
    float2* minv  = (float2*)w; w += (size_t)N_NODES * 8 * 8;
    float* alpha2 = (float*)w;  w += (size_t)E_TOT * 4;
    int* cnt    = (int*)w; w += (size_t)N_NODES * 4;
    int* offs   = (int*)w; w += (size_t)(N_NODES + 1) * 4;
    int* cursor = (int*)w; w += (size_t)(N_NODES + 4) * 4;
    int* bsum   = (int*)w; w += (size_t)NB_SCAN * 4;
    int* boffs  = (int*)w; w += (size_t)NB_SCAN * 4;
    int* csr    = (int*)w; w += (size_t)E_TOT * 4;

    hipMemsetAsync(cnt, 0, (size_t)N_NODES * 4, stream);
    hist_k<<<(E_TOT + 255) / 256, 256, 0, stream>>>(ei, cnt);
    scanA_k<<<NB_SCAN, 256, 0, stream>>>(cnt, offs, bsum);
    scanB_k<<<1, 256, 0, stream>>>(bsum, boffs);
    scanC_k<<<NB_SCAN, 256, 0, stream>>>(boffs, offs, cursor);
    scat_k<<<(E_TOT + 255) / 256, 256, 0, stream>>>(ei, cursor, csr);

    gemm1_k<<<(N_NODES + 63) / 64, 256, 0, stream>>>(x, W1, a1s, a1d, h1u, s1s, s1d);
    stats1_k<<<(N_NODES + 3) / 4, 256, 0, stream>>>(csr, offs, s1s, s1d, minv);
    agg1_k<<<N_NODES / 2, 256, 0, stream>>>(csr, offs, h1u, s1s, s1d, minv, b1, hr);
    gemm2_k<<<(N_NODES + 31) / 32, 256, 0, stream>>>(hr, W2, a2s, a2d, h2u, s2s, s2d);
    stats2_k<<<(N_NODES + 3) / 4, 256, 0, stream>>>(csr, offs, s2s, s2d, alpha2);
    agg2_k<<<(N_NODES + 7) / 8, 256, 0, stream>>>(csr, offs, h2u, alpha2, b2, out);
}

// Round 5
// 348.448 us; speedup vs baseline: 1.4958x; 1.0720x over previous
//
#include <hip/hip_runtime.h>
#include <hip/hip_fp16.h>
#include <math.h>

#define N_NODES 50000
#define N_EDGES 800000
#define E_TOT (N_EDGES + N_NODES)
#define NB_SCAN ((N_NODES + 255) / 256)

typedef unsigned int uint;
typedef unsigned short ushort;

__device__ __forceinline__ ushort f2bf(float f) {          // RNE f32->bf16
    uint u = __float_as_uint(f);
    return (ushort)((u + 0x7FFFu + ((u >> 16) & 1u)) >> 16);
}
__device__ __forceinline__ float bf2f(ushort u) {
    return __uint_as_float((uint)u << 16);
}
__device__ __forceinline__ float bflo(uint v) { return __uint_as_float(v << 16); }
__device__ __forceinline__ float bfhi(uint v) { return __uint_as_float(v & 0xFFFF0000u); }

// ---------------- CSR build ----------------

__global__ void hist_k(const int* __restrict__ ei, int* __restrict__ cnt) {
    int e = blockIdx.x * blockDim.x + threadIdx.x;
    if (e < N_EDGES)      atomicAdd(&cnt[ei[N_EDGES + e]], 1);
    else if (e < E_TOT)   atomicAdd(&cnt[e - N_EDGES], 1);
}

__global__ __launch_bounds__(256) void scanA_k(const int* __restrict__ cnt,
                                               int* __restrict__ offs,
                                               int* __restrict__ bsum) {
    __shared__ int ws[4];
    int b = blockIdx.x, tid = threadIdx.x;
    int i = b * 256 + tid;
    int v = (i < N_NODES) ? cnt[i] : 0;
    int lane = tid & 63, w = tid >> 6;
    int x = v;
    #pragma unroll
    for (int d = 1; d < 64; d <<= 1) {
        int y = __shfl_up(x, d);
        if (lane >= d) x += y;
    }
    if (lane == 63) ws[w] = x;
    __syncthreads();
    if (tid == 0) {
        int s = 0;
        #pragma unroll
        for (int j = 0; j < 4; j++) { s += ws[j]; ws[j] = s; }
    }
    __syncthreads();
    int incl = x + (w ? ws[w - 1] : 0);
    if (i < N_NODES) offs[i + 1] = incl;
    if (tid == 255) bsum[b] = incl;
}

__global__ __launch_bounds__(256) void scanB_k(const int* __restrict__ bsum,
                                               int* __restrict__ boffs) {
    __shared__ int ws[4];
    int tid = threadIdx.x;
    int v = (tid < NB_SCAN) ? bsum[tid] : 0;
    int lane = tid & 63, w = tid >> 6;
    int x = v;
    #pragma unroll
    for (int d = 1; d < 64; d <<= 1) {
        int y = __shfl_up(x, d);
        if (lane >= d) x += y;
    }
    if (lane == 63) ws[w] = x;
    __syncthreads();
    if (tid == 0) {
        int s = 0;
        #pragma unroll
        for (int j = 0; j < 4; j++) { s += ws[j]; ws[j] = s; }
    }
    __syncthreads();
    int incl = x + (w ? ws[w - 1] : 0);
    if (tid < NB_SCAN) boffs[tid] = incl - v;
}

__global__ __launch_bounds__(256) void scanC_k(const int* __restrict__ boffs,
                                               int* __restrict__ offs,
                                               int* __restrict__ cursor) {
    int b = blockIdx.x;
    int i = b * 256 + threadIdx.x;
    if (i == 0) { offs[0] = 0; cursor[0] = 0; }
    if (i < N_NODES) {
        int v = offs[i + 1] + boffs[b];
        offs[i + 1] = v;
        cursor[i + 1] = v;
    }
}

__global__ void scat_k(const int* __restrict__ ei, int* __restrict__ cursor,
                       int* __restrict__ csr) {
    int e = blockIdx.x * blockDim.x + threadIdx.x;
    int s, d;
    if (e < N_EDGES)      { s = ei[e]; d = ei[N_EDGES + e]; }
    else if (e < E_TOT)   { s = e - N_EDGES; d = s; }
    else return;
    int p = atomicAdd(&cursor[d], 1);
    csr[p] = s;
}

// ---------------- Layer 1 GEMM (64x256 tile, 16x4 per thread, LDS broadcast) --

__global__ __launch_bounds__(256) void gemm1_k(
        const float* __restrict__ x, const float* __restrict__ W1,
        const float* __restrict__ a1s, const float* __restrict__ a1d,
        ushort* __restrict__ h1u, float* __restrict__ s1s,
        float* __restrict__ s1d) {
    __shared__ float xs[64][128];
    int tid = threadIdx.x;
    int row0 = blockIdx.x * 64;
    for (int i = tid; i < 64 * 32; i += 256) {
        int r = i >> 5, q = i & 31;
        int row = row0 + r; if (row >= N_NODES) row = N_NODES - 1;
        float4 v = ((const float4*)(x + (size_t)row * 128))[q];
        *((float4*)&xs[r][q * 4]) = v;
    }
    __syncthreads();
    int lane = tid & 63, wv = tid >> 6;
    int c0 = lane * 4;
    int rbase = wv * 16;
    float acc[16][4];
    #pragma unroll
    for (int r = 0; r < 16; r++)
        #pragma unroll
        for (int j = 0; j < 4; j++) acc[r][j] = 0.f;

    for (int k = 0; k < 128; k += 4) {
        float4 w0 = *((const float4*)(W1 + (size_t)(k + 0) * 256 + c0));
        float4 w1 = *((const float4*)(W1 + (size_t)(k + 1) * 256 + c0));
        float4 w2 = *((const float4*)(W1 + (size_t)(k + 2) * 256 + c0));
        float4 w3 = *((const float4*)(W1 + (size_t)(k + 3) * 256 + c0));
        #pragma unroll
        for (int r = 0; r < 16; r++) {
            float4 xv = *((const float4*)&xs[rbase + r][k]);   // broadcast read
            acc[r][0] = fmaf(xv.x, w0.x, acc[r][0]);
            acc[r][1] = fmaf(xv.x, w0.y, acc[r][1]);
            acc[r][2] = fmaf(xv.x, w0.z, acc[r][2]);
            acc[r][3] = fmaf(xv.x, w0.w, acc[r][3]);
            acc[r][0] = fmaf(xv.y, w1.x, acc[r][0]);
            acc[r][1] = fmaf(xv.y, w1.y, acc[r][1]);
            acc[r][2] = fmaf(xv.y, w1.z, acc[r][2]);
            acc[r][3] = fmaf(xv.y, w1.w, acc[r][3]);
            acc[r][0] = fmaf(xv.z, w2.x, acc[r][0]);
            acc[r][1] = fmaf(xv.z, w2.y, acc[r][1]);
            acc[r][2] = fmaf(xv.z, w2.z, acc[r][2]);
            acc[r][3] = fmaf(xv.z, w2.w, acc[r][3]);
            acc[r][0] = fmaf(xv.w, w3.x, acc[r][0]);
            acc[r][1] = fmaf(xv.w, w3.y, acc[r][1]);
            acc[r][2] = fmaf(xv.w, w3.z, acc[r][2]);
            acc[r][3] = fmaf(xv.w, w3.w, acc[r][3]);
        }
    }

    float as0 = a1s[c0], as1 = a1s[c0 + 1], as2 = a1s[c0 + 2], as3 = a1s[c0 + 3];
    float ad0 = a1d[c0], ad1 = a1d[c0 + 1], ad2 = a1d[c0 + 2], ad3 = a1d[c0 + 3];
    int h = lane >> 3;
    #pragma unroll 4
    for (int r = 0; r < 16; r++) {
        int row = row0 + rbase + r;
        float ps = acc[r][0] * as0 + acc[r][1] * as1 + acc[r][2] * as2 + acc[r][3] * as3;
        float pd = acc[r][0] * ad0 + acc[r][1] * ad1 + acc[r][2] * ad2 + acc[r][3] * ad3;
        #pragma unroll
        for (int mask = 1; mask <= 4; mask <<= 1) {
            ps += __shfl_xor(ps, mask);
            pd += __shfl_xor(pd, mask);
        }
        if (row < N_NODES) {
            uint lo = (uint)f2bf(acc[r][0]) | ((uint)f2bf(acc[r][1]) << 16);
            uint hi = (uint)f2bf(acc[r][2]) | ((uint)f2bf(acc[r][3]) << 16);
            *((uint2*)(h1u + (size_t)row * 256 + c0)) = make_uint2(lo, hi);
            if ((lane & 7) == 0) {
                s1s[row * 8 + h] = ps;
                s1d[row * 8 + h] = pd;
            }
        }
    }
}

// ---------------- Layer 1 softmax stats + fp16 alpha materialization ----------

__global__ __launch_bounds__(256) void stats1_k(
        const int* __restrict__ csr, const int* __restrict__ offs,
        const float* __restrict__ s1s, const float* __restrict__ s1d,
        __half* __restrict__ alpha) {
    int n = blockIdx.x * 4 + (threadIdx.x >> 6);
    if (n >= N_NODES) return;
    int lane = threadIdx.x & 63;
    int e8 = lane >> 3, h = lane & 7;
    int beg = offs[n], end = offs[n + 1];
    float sd = s1d[n * 8 + h];
    float m = -3.4e38f, d = 0.f;
    for (int i = beg + e8; i < end; i += 8) {
        int s = csr[i];
        float e = s1s[s * 8 + h] + sd;
        e = (e >= 0.f) ? e : 0.2f * e;
        float mn = fmaxf(m, e);
        d = d * __expf(m - mn) + __expf(e - mn);
        m = mn;
    }
    #pragma unroll
    for (int mask = 8; mask <= 32; mask <<= 1) {
        float om = __shfl_xor(m, mask);
        float od = __shfl_xor(d, mask);
        float nm = fmaxf(m, om);
        d = d * __expf(m - nm) + od * __expf(om - nm);
        m = nm;
    }
    float inv = 1.f / (d + 1e-16f);
    for (int i = beg + e8; i < end; i += 8) {
        int s = csr[i];
        float e = s1s[s * 8 + h] + sd;
        e = (e >= 0.f) ? e : 0.2f * e;
        alpha[(size_t)i * 8 + h] = __float2half(__expf(e - m) * inv);
    }
}

// ---------------- Layer 1 aggregation: pure bf16 gather ----------------
// 4 nodes / block, 64 lanes / node, 4 channels (uint2) / lane.

__global__ __launch_bounds__(256) void agg1_k(
        const int* __restrict__ csr, const int* __restrict__ offs,
        const ushort* __restrict__ h1u, const __half* __restrict__ alpha,
        const float* __restrict__ b1, float* __restrict__ hr) {
    int lane = threadIdx.x & 63;
    int n = blockIdx.x * 4 + (threadIdx.x >> 6);
    int h = lane >> 3;                    // head of channels 4*lane..4*lane+3
    int beg = offs[n], end = offs[n + 1];
    const uint2* hv = (const uint2*)h1u;  // row = 64 uint2
    float acc0 = 0.f, acc1 = 0.f, acc2 = 0.f, acc3 = 0.f;
    int i = beg;
    for (; i + 1 < end; i += 2) {
        int s0 = csr[i], s1 = csr[i + 1];
        float a0 = __half2float(alpha[(size_t)i * 8 + h]);
        float a1 = __half2float(alpha[(size_t)(i + 1) * 8 + h]);
        uint2 v0 = hv[(size_t)s0 * 64 + lane];
        uint2 v1 = hv[(size_t)s1 * 64 + lane];
        acc0 = fmaf(a0, bflo(v0.x), acc0);
        acc1 = fmaf(a0, bfhi(v0.x), acc1);
        acc2 = fmaf(a0, bflo(v0.y), acc2);
        acc3 = fmaf(a0, bfhi(v0.y), acc3);
        acc0 = fmaf(a1, bflo(v1.x), acc0);
        acc1 = fmaf(a1, bfhi(v1.x), acc1);
        acc2 = fmaf(a1, bflo(v1.y), acc2);
        acc3 = fmaf(a1, bfhi(v1.y), acc3);
    }
    if (i < end) {
        int s0 = csr[i];
        float a0 = __half2float(alpha[(size_t)i * 8 + h]);
        uint2 v0 = hv[(size_t)s0 * 64 + lane];
        acc0 = fmaf(a0, bflo(v0.x), acc0);
        acc1 = fmaf(a0, bfhi(v0.x), acc1);
        acc2 = fmaf(a0, bflo(v0.y), acc2);
        acc3 = fmaf(a0, bfhi(v0.y), acc3);
    }
    int c0 = 4 * lane;
    float4 bv = *((const float4*)(b1 + c0));
    float4 o;
    o.x = fmaxf(acc0 + bv.x, 0.f);
    o.y = fmaxf(acc1 + bv.y, 0.f);
    o.z = fmaxf(acc2 + bv.z, 0.f);
    o.w = fmaxf(acc3 + bv.w, 0.f);
    ((float4*)hr)[(size_t)n * 64 + lane] = o;    // ReLU between layers
}

// ---------------- Layer 2 GEMM (32-row tile, 4x1 per thread, LDS broadcast) --

__global__ __launch_bounds__(256) void gemm2_k(
        const float* __restrict__ hr, const float* __restrict__ W2,
        const float* __restrict__ a2s, const float* __restrict__ a2d,
        ushort* __restrict__ h2u, float* __restrict__ s2s,
        float* __restrict__ s2d) {
    __shared__ float hs[32][256];
    int tid = threadIdx.x;
    int row0 = blockIdx.x * 32;
    for (int i = tid; i < 32 * 64; i += 256) {
        int r = i >> 6, q = i & 63;
        int row = row0 + r; if (row >= N_NODES) row = N_NODES - 1;
        float4 v = ((const float4*)(hr + (size_t)row * 256))[q];
        *((float4*)&hs[r][q * 4]) = v;
    }
    __syncthreads();
    int c = tid & 31, g = tid >> 5;       // rows g*4 .. g*4+3
    float acc[4] = {0.f, 0.f, 0.f, 0.f};
    for (int k = 0; k < 256; k += 4) {
        float w0 = W2[(size_t)(k + 0) * 32 + c];
        float w1 = W2[(size_t)(k + 1) * 32 + c];
        float w2 = W2[(size_t)(k + 2) * 32 + c];
        float w3 = W2[(size_t)(k + 3) * 32 + c];
        #pragma unroll
        for (int r = 0; r < 4; r++) {
            float4 xv = *((const float4*)&hs[g * 4 + r][k]);
            acc[r] = fmaf(xv.x, w0, acc[r]);
            acc[r] = fmaf(xv.y, w1, acc[r]);
            acc[r] = fmaf(xv.z, w2, acc[r]);
            acc[r] = fmaf(xv.w, w3, acc[r]);
        }
    }
    float av_s = a2s[c], av_d = a2d[c];
    #pragma unroll
    for (int r = 0; r < 4; r++) {
        int row = row0 + g * 4 + r;
        float ps = acc[r] * av_s, pd = acc[r] * av_d;
        #pragma unroll
        for (int mask = 16; mask >= 1; mask >>= 1) {
            ps += __shfl_xor(ps, mask);
            pd += __shfl_xor(pd, mask);
        }
        if (row < N_NODES) {
            h2u[(size_t)row * 32 + c] = f2bf(acc[r]);
            if (c == 0) { s2s[row] = ps; s2d[row] = pd; }
        }
    }
}

// ---------------- Layer 2 softmax stats + alpha ----------------

__global__ __launch_bounds__(256) void stats2_k(
        const int* __restrict__ csr, const int* __restrict__ offs,
        const float* __restrict__ s2s, const float* __restrict__ s2d,
        float* __restrict__ alpha2) {
    int n = blockIdx.x * 4 + (threadIdx.x >> 6);
    if (n >= N_NODES) return;
    int lane = threadIdx.x & 63;
    int beg = offs[n], end = offs[n + 1];
    float sd = s2d[n];
    float m = -3.4e38f, d = 0.f;
    for (int i = beg + lane; i < end; i += 64) {
        int s = csr[i];
        float e = s2s[s] + sd;
        e = (e >= 0.f) ? e : 0.2f * e;
        float mn = fmaxf(m, e);
        d = d * __expf(m - mn) + __expf(e - mn);
        m = mn;
    }
    #pragma unroll
    for (int mask = 1; mask <= 32; mask <<= 1) {
        float om = __shfl_xor(m, mask);
        float od = __shfl_xor(d, mask);
        float nm = fmaxf(m, om);
        d = d * __expf(m - nm) + od * __expf(om - nm);
        m = nm;
    }
    float inv = 1.f / (d + 1e-16f);
    for (int i = beg + lane; i < end; i += 64) {
        int s = csr[i];
        float e = s2s[s] + sd;
        e = (e >= 0.f) ? e : 0.2f * e;
        alpha2[i] = __expf(e - m) * inv;
    }
}

// ---------------- Layer 2 aggregation ----------------

__global__ __launch_bounds__(256) void agg2_k(
        const int* __restrict__ csr, const int* __restrict__ offs,
        const ushort* __restrict__ h2u, const float* __restrict__ alpha2,
        const float* __restrict__ b2, float* __restrict__ out) {
    int n = blockIdx.x * 8 + (threadIdx.x >> 5);
    int c = threadIdx.x & 31;
    if (n >= N_NODES) return;
    int beg = offs[n], end = offs[n + 1];
    float acc = 0.f;
    int i = beg;
    for (; i + 1 < end; i += 2) {
        int s0 = csr[i], s1 = csr[i + 1];
        float a0 = alpha2[i], a1v = alpha2[i + 1];
        acc = fmaf(a0, bf2f(h2u[(size_t)s0 * 32 + c]), acc);
        acc = fmaf(a1v, bf2f(h2u[(size_t)s1 * 32 + c]), acc);
    }
    if (i < end)
        acc = fmaf(alpha2[i], bf2f(h2u[(size_t)csr[i] * 32 + c]), acc);
    out[(size_t)n * 32 + c] = acc + b2[c];
}

// ---------------- launch ----------------

extern "C" void kernel_launch(void* const* d_in, const int* in_sizes, int n_in,
                              void* d_out, int out_size, void* d_ws, size_t ws_size,
                              hipStream_t stream) {
    const float* x   = (const float*)d_in[0];
    const int*   ei  = (const int*)d_in[1];
    const float* W1  = (const float*)d_in[2];
    const float* a1s = (const float*)d_in[3];
    const float* a1d = (const float*)d_in[4];
    const float* b1  = (const float*)d_in[5];
    const float* W2  = (const float*)d_in[6];
    const float* a2s = (const float*)d_in[7];
    const float* a2d = (const float*)d_in[8];
    const float* b2  = (const float*)d_in[9];
    float* out = (float*)d_out;

    char* w = (char*)d_ws;
    float* hr     = (float*)w;  w += (size_t)N_NODES * 256 * 4;
    ushort* h1u   = (ushort*)w; w += (size_t)N_NODES * 256 * 2;
    ushort* h2u   = (ushort*)w; w += (size_t)N_NODES * 32 * 2;
    float* s1s    = (float*)w;  w += (size_t)N_NODES * 8 * 4;
    float* s1d    = (float*)w;  w += (size_t)N_NODES * 8 * 4;
    float* s2s    = (float*)w;  w += (size_t)N_NODES * 4;
    float* s2d    = (float*)w;  w += (size_t)N_NODES * 4;
    __half* alpha = (__half*)w; w += (size_t)E_TOT * 8 * 2;
    float* alpha2 = (float*)w;  w += (size_t)E_TOT * 4;
    int* cnt    = (int*)w; w += (size_t)N_NODES * 4;
    int* offs   = (int*)w; w += (size_t)(N_NODES + 1) * 4;
    int* cursor = (int*)w; w += (size_t)(N_NODES + 4) * 4;
    int* bsum   = (int*)w; w += (size_t)NB_SCAN * 4;
    int* boffs  = (int*)w; w += (size_t)NB_SCAN * 4;
    int* csr    = (int*)w; w += (size_t)E_TOT * 4;

    hipMemsetAsync(cnt, 0, (size_t)N_NODES * 4, stream);
    hist_k<<<(E_TOT + 255) / 256, 256, 0, stream>>>(ei, cnt);
    scanA_k<<<NB_SCAN, 256, 0, stream>>>(cnt, offs, bsum);
    scanB_k<<<1, 256, 0, stream>>>(bsum, boffs);
    scanC_k<<<NB_SCAN, 256, 0, stream>>>(boffs, offs, cursor);
    scat_k<<<(E_TOT + 255) / 256, 256, 0, stream>>>(ei, cursor, csr);

    gemm1_k<<<(N_NODES + 63) / 64, 256, 0, stream>>>(x, W1, a1s, a1d, h1u, s1s, s1d);
    stats1_k<<<(N_NODES + 3) / 4, 256, 0, stream>>>(csr, offs, s1s, s1d, alpha);
    agg1_k<<<(N_NODES + 3) / 4, 256, 0, stream>>>(csr, offs, h1u, alpha, b1, hr);
    gemm2_k<<<(N_NODES + 31) / 32, 256, 0, stream>>>(hr, W2, a2s, a2d, h2u, s2s, s2d);
    stats2_k<<<(N_NODES + 3) / 4, 256, 0, stream>>>(csr, offs, s2s, s2d, alpha2);
    agg2_k<<<(N_NODES + 7) / 8, 256, 0, stream>>>(csr, offs, h2u, alpha2, b2, out);
}

// Round 6
// 321.865 us; speedup vs baseline: 1.6194x; 1.0826x over previous
//
#include <hip/hip_runtime.h>
#include <hip/hip_fp16.h>
#include <math.h>

#define N_NODES 50000
#define N_EDGES 800000
#define E_TOT (N_EDGES + N_NODES)
#define NB_SCAN ((N_NODES + 255) / 256)
#define N_RT 3125                 // N_NODES / 16 row-tiles

typedef unsigned int uint;
typedef unsigned short ushort;
typedef float f32x4 __attribute__((ext_vector_type(4)));
typedef short v8s __attribute__((ext_vector_type(8)));

__device__ __forceinline__ ushort f2bf(float f) {          // RNE f32->bf16
    uint u = __float_as_uint(f);
    return (ushort)((u + 0x7FFFu + ((u >> 16) & 1u)) >> 16);
}
__device__ __forceinline__ float bf2f(ushort u) {
    return __uint_as_float((uint)u << 16);
}
__device__ __forceinline__ float bflo(uint v) { return __uint_as_float(v << 16); }
__device__ __forceinline__ float bfhi(uint v) { return __uint_as_float(v & 0xFFFF0000u); }

// k-position inside a 32-k block for fragment lane-group g, elem j (consistent A/B)
__device__ __forceinline__ int kmap(int g, int j) {
    return ((j >> 2) << 4) + (g << 2) + (j & 3);
}

// ---------------- CSR build ----------------

__global__ void hist_k(const int* __restrict__ ei, int* __restrict__ cnt) {
    int e = blockIdx.x * blockDim.x + threadIdx.x;
    if (e < N_EDGES)      atomicAdd(&cnt[ei[N_EDGES + e]], 1);
    else if (e < E_TOT)   atomicAdd(&cnt[e - N_EDGES], 1);
}

__global__ __launch_bounds__(256) void scanA_k(const int* __restrict__ cnt,
                                               int* __restrict__ offs,
                                               int* __restrict__ bsum) {
    __shared__ int ws[4];
    int b = blockIdx.x, tid = threadIdx.x;
    int i = b * 256 + tid;
    int v = (i < N_NODES) ? cnt[i] : 0;
    int lane = tid & 63, w = tid >> 6;
    int x = v;
    #pragma unroll
    for (int d = 1; d < 64; d <<= 1) {
        int y = __shfl_up(x, d);
        if (lane >= d) x += y;
    }
    if (lane == 63) ws[w] = x;
    __syncthreads();
    if (tid == 0) {
        int s = 0;
        #pragma unroll
        for (int j = 0; j < 4; j++) { s += ws[j]; ws[j] = s; }
    }
    __syncthreads();
    int incl = x + (w ? ws[w - 1] : 0);
    if (i < N_NODES) offs[i + 1] = incl;
    if (tid == 255) bsum[b] = incl;
}

__global__ __launch_bounds__(256) void scanB_k(const int* __restrict__ bsum,
                                               int* __restrict__ boffs) {
    __shared__ int ws[4];
    int tid = threadIdx.x;
    int v = (tid < NB_SCAN) ? bsum[tid] : 0;
    int lane = tid & 63, w = tid >> 6;
    int x = v;
    #pragma unroll
    for (int d = 1; d < 64; d <<= 1) {
        int y = __shfl_up(x, d);
        if (lane >= d) x += y;
    }
    if (lane == 63) ws[w] = x;
    __syncthreads();
    if (tid == 0) {
        int s = 0;
        #pragma unroll
        for (int j = 0; j < 4; j++) { s += ws[j]; ws[j] = s; }
    }
    __syncthreads();
    int incl = x + (w ? ws[w - 1] : 0);
    if (tid < NB_SCAN) boffs[tid] = incl - v;
}

__global__ __launch_bounds__(256) void scanC_k(const int* __restrict__ boffs,
                                               int* __restrict__ offs,
                                               int* __restrict__ cursor) {
    int b = blockIdx.x;
    int i = b * 256 + threadIdx.x;
    if (i == 0) { offs[0] = 0; cursor[0] = 0; }
    if (i < N_NODES) {
        int v = offs[i + 1] + boffs[b];
        offs[i + 1] = v;
        cursor[i + 1] = v;
    }
}

__global__ void scat_k(const int* __restrict__ ei, int* __restrict__ cursor,
                       int* __restrict__ csr) {
    int e = blockIdx.x * blockDim.x + threadIdx.x;
    int s, d;
    if (e < N_EDGES)      { s = ei[e]; d = ei[N_EDGES + e]; }
    else if (e < E_TOT)   { s = e - N_EDGES; d = s; }
    else return;
    int p = atomicAdd(&cursor[d], 1);
    csr[p] = s;
}

// ---------------- AT[j][k] = sum_d W1[k][h*32+d] * a(j)[d]   (16 x 128 f32) ----

__global__ void w1a_k(const float* __restrict__ W1, const float* __restrict__ a1s,
                      const float* __restrict__ a1d, float* __restrict__ AT) {
    int idx = blockIdx.x * 256 + threadIdx.x;    // 0..2047
    if (idx >= 2048) return;
    int j = idx >> 7, k = idx & 127;
    int h = (j < 8) ? j : j - 8;
    const float* a = (j < 8) ? (a1s + h * 32) : (a1d + h * 32);
    const float* wrow = W1 + (size_t)k * 256 + h * 32;
    float s = 0.f;
    #pragma unroll 8
    for (int d = 0; d < 32; d++) s = fmaf(wrow[d], a[d], s);
    AT[j * 128 + k] = s;
}

// ---------------- W1 -> fragment-packed bf16 [16ct][4ks][64lane][8j] ----------

__global__ void w1f_k(const float* __restrict__ W1, ushort* __restrict__ W1f) {
    int idx = blockIdx.x * 256 + threadIdx.x;    // 0..4095
    if (idx >= 4096) return;
    int lane = idx & 63, ks = (idx >> 6) & 3, ct = idx >> 8;
    int g = lane >> 4, col = ct * 16 + (lane & 15);
    ushort us[8];
    #pragma unroll
    for (int j = 0; j < 8; j++) {
        int k = ks * 32 + kmap(g, j);
        us[j] = f2bf(W1[(size_t)k * 256 + col]);
    }
    uint4 pk;
    pk.x = (uint)us[0] | ((uint)us[1] << 16);
    pk.y = (uint)us[2] | ((uint)us[3] << 16);
    pk.z = (uint)us[4] | ((uint)us[5] << 16);
    pk.w = (uint)us[6] | ((uint)us[7] << 16);
    *((uint4*)(W1f + ((size_t)(ct * 4 + ks) * 64 + lane) * 8)) = pk;
}

// ---------------- prep: x -> frag-packed bf16 + exact f32 scores ----------------
// Block: 64 rows. Waves 0..3 each pack one 16-row tile; then all threads
// compute s1s/s1d = x @ AT (exact f32, reassociated only).

__global__ __launch_bounds__(256) void prep_k(
        const float* __restrict__ x, const float* __restrict__ AT,
        ushort* __restrict__ xbf, float* __restrict__ s1s,
        float* __restrict__ s1d) {
    __shared__ float xs[64][132];
    __shared__ float at[16][132];
    int tid = threadIdx.x;
    int row0 = blockIdx.x * 64;
    for (int i = tid; i < 64 * 32; i += 256) {
        int r = i >> 5, q = i & 31;
        int row = row0 + r; if (row >= N_NODES) row = N_NODES - 1;
        float4 v = ((const float4*)(x + (size_t)row * 128))[q];
        *((float4*)&xs[r][q * 4]) = v;
    }
    for (int i = tid; i < 16 * 32; i += 256) {
        int j = i >> 5, q = i & 31;
        float4 v = ((const float4*)(AT + j * 128))[q];
        *((float4*)&at[j][q * 4]) = v;
    }
    __syncthreads();

    // fragment pack (one row-tile per wave)
    int lane = tid & 63, wv = tid >> 6;
    int rt = blockIdx.x * 4 + wv;
    if (rt < N_RT) {
        int rloc = wv * 16 + (lane & 15);
        int g = lane >> 4;
        #pragma unroll
        for (int ks = 0; ks < 4; ks++) {
            ushort us[8];
            #pragma unroll
            for (int j = 0; j < 8; j++)
                us[j] = f2bf(xs[rloc][ks * 32 + kmap(g, j)]);
            uint4 pk;
            pk.x = (uint)us[0] | ((uint)us[1] << 16);
            pk.y = (uint)us[2] | ((uint)us[3] << 16);
            pk.z = (uint)us[4] | ((uint)us[5] << 16);
            pk.w = (uint)us[6] | ((uint)us[7] << 16);
            *((uint4*)(xbf + (((size_t)rt * 4 + ks) * 64 + lane) * 8)) = pk;
        }
    }

    // exact f32 scores: row = tid>>2, thread handles 4 of 16 score columns
    int row = tid >> 2;
    int jg = tid & 3;
    float acc[4] = {0.f, 0.f, 0.f, 0.f};
    for (int k4 = 0; k4 < 32; k4++) {
        float4 xv = *((float4*)&xs[row][k4 * 4]);
        #pragma unroll
        for (int jq = 0; jq < 4; jq++) {
            int j = jg * 4 + jq;
            float4 av = *((float4*)&at[j][k4 * 4]);
            acc[jq] += xv.x * av.x + xv.y * av.y + xv.z * av.z + xv.w * av.w;
        }
    }
    int grow = row0 + row;
    if (grow < N_NODES) {
        #pragma unroll
        for (int jq = 0; jq < 4; jq++) {
            int j = jg * 4 + jq;
            if (j < 8) s1s[grow * 8 + j] = acc[jq];
            else       s1d[grow * 8 + (j - 8)] = acc[jq];
        }
    }
}

// ---------------- Layer 1 GEMM: bf16 MFMA 16x16x32, 1 row-tile / wave ----------

__global__ __launch_bounds__(256) void gemm1_k(
        const ushort* __restrict__ xbf, const ushort* __restrict__ W1f,
        ushort* __restrict__ h1u) {
    int lane = threadIdx.x & 63, wv = threadIdx.x >> 6;
    int rt = blockIdx.x * 4 + wv;
    if (rt >= N_RT) return;
    f32x4 acc[16];
    #pragma unroll
    for (int ct = 0; ct < 16; ct++) acc[ct] = (f32x4){0.f, 0.f, 0.f, 0.f};
    const v8s* ap = (const v8s*)(xbf) + (size_t)rt * 4 * 64;
    const v8s* bp = (const v8s*)(W1f);
    #pragma unroll
    for (int ks = 0; ks < 4; ks++) {
        v8s a = ap[ks * 64 + lane];
        #pragma unroll
        for (int ct = 0; ct < 16; ct++) {
            v8s b = bp[(ct * 4 + ks) * 64 + lane];
            acc[ct] = __builtin_amdgcn_mfma_f32_16x16x32_bf16(a, b, acc[ct], 0, 0, 0);
        }
    }
    int r0 = rt * 16 + (lane >> 4) * 4;
    int cb = lane & 15;
    #pragma unroll
    for (int ct = 0; ct < 16; ct++) {
        #pragma unroll
        for (int q = 0; q < 4; q++)
            h1u[(size_t)(r0 + q) * 256 + ct * 16 + cb] = f2bf(acc[ct][q]);
    }
}

// ---------------- Layer 1 softmax stats + fp16 alpha materialization ----------

__global__ __launch_bounds__(256) void stats1_k(
        const int* __restrict__ csr, const int* __restrict__ offs,
        const float* __restrict__ s1s, const float* __restrict__ s1d,
        __half* __restrict__ alpha) {
    int n = blockIdx.x * 4 + (threadIdx.x >> 6);
    if (n >= N_NODES) return;
    int lane = threadIdx.x & 63;
    int e8 = lane >> 3, h = lane & 7;
    int beg = offs[n], end = offs[n + 1];
    float sd = s1d[n * 8 + h];
    float m = -3.4e38f, d = 0.f;
    for (int i = beg + e8; i < end; i += 8) {
        int s = csr[i];
        float e = s1s[s * 8 + h] + sd;
        e = (e >= 0.f) ? e : 0.2f * e;
        float mn = fmaxf(m, e);
        d = d * __expf(m - mn) + __expf(e - mn);
        m = mn;
    }
    #pragma unroll
    for (int mask = 8; mask <= 32; mask <<= 1) {
        float om = __shfl_xor(m, mask);
        float od = __shfl_xor(d, mask);
        float nm = fmaxf(m, om);
        d = d * __expf(m - nm) + od * __expf(om - nm);
        m = nm;
    }
    float inv = 1.f / (d + 1e-16f);
    for (int i = beg + e8; i < end; i += 8) {
        int s = csr[i];
        float e = s1s[s * 8 + h] + sd;
        e = (e >= 0.f) ? e : 0.2f * e;
        alpha[(size_t)i * 8 + h] = __float2half(__expf(e - m) * inv);
    }
}

// ---------------- Layer 1 aggregation: pure bf16 gather ----------------
// 4 nodes / block, 64 lanes / node, 4 channels (uint2) / lane.

__global__ __launch_bounds__(256) void agg1_k(
        const int* __restrict__ csr, const int* __restrict__ offs,
        const ushort* __restrict__ h1u, const __half* __restrict__ alpha,
        const float* __restrict__ b1, float* __restrict__ hr) {
    int lane = threadIdx.x & 63;
    int n = blockIdx.x * 4 + (threadIdx.x >> 6);
    int h = lane >> 3;
    int beg = offs[n], end = offs[n + 1];
    const uint2* hv = (const uint2*)h1u;
    float acc0 = 0.f, acc1 = 0.f, acc2 = 0.f, acc3 = 0.f;
    int i = beg;
    for (; i + 1 < end; i += 2) {
        int s0 = csr[i], s1 = csr[i + 1];
        float a0 = __half2float(alpha[(size_t)i * 8 + h]);
        float a1 = __half2float(alpha[(size_t)(i + 1) * 8 + h]);
        uint2 v0 = hv[(size_t)s0 * 64 + lane];
        uint2 v1 = hv[(size_t)s1 * 64 + lane];
        acc0 = fmaf(a0, bflo(v0.x), acc0);
        acc1 = fmaf(a0, bfhi(v0.x), acc1);
        acc2 = fmaf(a0, bflo(v0.y), acc2);
        acc3 = fmaf(a0, bfhi(v0.y), acc3);
        acc0 = fmaf(a1, bflo(v1.x), acc0);
        acc1 = fmaf(a1, bfhi(v1.x), acc1);
        acc2 = fmaf(a1, bflo(v1.y), acc2);
        acc3 = fmaf(a1, bfhi(v1.y), acc3);
    }
    if (i < end) {
        int s0 = csr[i];
        float a0 = __half2float(alpha[(size_t)i * 8 + h]);
        uint2 v0 = hv[(size_t)s0 * 64 + lane];
        acc0 = fmaf(a0, bflo(v0.x), acc0);
        acc1 = fmaf(a0, bfhi(v0.x), acc1);
        acc2 = fmaf(a0, bflo(v0.y), acc2);
        acc3 = fmaf(a0, bfhi(v0.y), acc3);
    }
    int c0 = 4 * lane;
    float4 bv = *((const float4*)(b1 + c0));
    float4 o;
    o.x = fmaxf(acc0 + bv.x, 0.f);
    o.y = fmaxf(acc1 + bv.y, 0.f);
    o.z = fmaxf(acc2 + bv.z, 0.f);
    o.w = fmaxf(acc3 + bv.w, 0.f);
    ((float4*)hr)[(size_t)n * 64 + lane] = o;    // ReLU between layers
}

// ---------------- Layer 2 GEMM (32-row tile, 4x1 per thread, LDS broadcast) --

__global__ __launch_bounds__(256) void gemm2_k(
        const float* __restrict__ hr, const float* __restrict__ W2,
        const float* __restrict__ a2s, const float* __restrict__ a2d,
        ushort* __restrict__ h2u, float* __restrict__ s2s,
        float* __restrict__ s2d) {
    __shared__ float hs[32][256];
    int tid = threadIdx.x;
    int row0 = blockIdx.x * 32;
    for (int i = tid; i < 32 * 64; i += 256) {
        int r = i >> 6, q = i & 63;
        int row = row0 + r; if (row >= N_NODES) row = N_NODES - 1;
        float4 v = ((const float4*)(hr + (size_t)row * 256))[q];
        *((float4*)&hs[r][q * 4]) = v;
    }
    __syncthreads();
    int c = tid & 31, g = tid >> 5;
    float acc[4] = {0.f, 0.f, 0.f, 0.f};
    for (int k = 0; k < 256; k += 4) {
        float w0 = W2[(size_t)(k + 0) * 32 + c];
        float w1 = W2[(size_t)(k + 1) * 32 + c];
        float w2 = W2[(size_t)(k + 2) * 32 + c];
        float w3 = W2[(size_t)(k + 3) * 32 + c];
        #pragma unroll
        for (int r = 0; r < 4; r++) {
            float4 xv = *((const float4*)&hs[g * 4 + r][k]);
            acc[r] = fmaf(xv.x, w0, acc[r]);
            acc[r] = fmaf(xv.y, w1, acc[r]);
            acc[r] = fmaf(xv.z, w2, acc[r]);
            acc[r] = fmaf(xv.w, w3, acc[r]);
        }
    }
    float av_s = a2s[c], av_d = a2d[c];
    #pragma unroll
    for (int r = 0; r < 4; r++) {
        int row = row0 + g * 4 + r;
        float ps = acc[r] * av_s, pd = acc[r] * av_d;
        #pragma unroll
        for (int mask = 16; mask >= 1; mask >>= 1) {
            ps += __shfl_xor(ps, mask);
            pd += __shfl_xor(pd, mask);
        }
        if (row < N_NODES) {
            h2u[(size_t)row * 32 + c] = f2bf(acc[r]);
            if (c == 0) { s2s[row] = ps; s2d[row] = pd; }
        }
    }
}

// ---------------- Layer 2 softmax stats + alpha ----------------

__global__ __launch_bounds__(256) void stats2_k(
        const int* __restrict__ csr, const int* __restrict__ offs,
        const float* __restrict__ s2s, const float* __restrict__ s2d,
        float* __restrict__ alpha2) {
    int n = blockIdx.x * 4 + (threadIdx.x >> 6);
    if (n >= N_NODES) return;
    int lane = threadIdx.x & 63;
    int beg = offs[n], end = offs[n + 1];
    float sd = s2d[n];
    float m = -3.4e38f, d = 0.f;
    for (int i = beg + lane; i < end; i += 64) {
        int s = csr[i];
        float e = s2s[s] + sd;
        e = (e >= 0.f) ? e : 0.2f * e;
        float mn = fmaxf(m, e);
        d = d * __expf(m - mn) + __expf(e - mn);
        m = mn;
    }
    #pragma unroll
    for (int mask = 1; mask <= 32; mask <<= 1) {
        float om = __shfl_xor(m, mask);
        float od = __shfl_xor(d, mask);
        float nm = fmaxf(m, om);
        d = d * __expf(m - nm) + od * __expf(om - nm);
        m = nm;
    }
    float inv = 1.f / (d + 1e-16f);
    for (int i = beg + lane; i < end; i += 64) {
        int s = csr[i];
        float e = s2s[s] + sd;
        e = (e >= 0.f) ? e : 0.2f * e;
        alpha2[i] = __expf(e - m) * inv;
    }
}

// ---------------- Layer 2 aggregation ----------------

__global__ __launch_bounds__(256) void agg2_k(
        const int* __restrict__ csr, const int* __restrict__ offs,
        const ushort* __restrict__ h2u, const float* __restrict__ alpha2,
        const float* __restrict__ b2, float* __restrict__ out) {
    int n = blockIdx.x * 8 + (threadIdx.x >> 5);
    int c = threadIdx.x & 31;
    if (n >= N_NODES) return;
    int beg = offs[n], end = offs[n + 1];
    float acc = 0.f;
    int i = beg;
    for (; i + 1 < end; i += 2) {
        int s0 = csr[i], s1 = csr[i + 1];
        float a0 = alpha2[i], a1v = alpha2[i + 1];
        acc = fmaf(a0, bf2f(h2u[(size_t)s0 * 32 + c]), acc);
        acc = fmaf(a1v, bf2f(h2u[(size_t)s1 * 32 + c]), acc);
    }
    if (i < end)
        acc = fmaf(alpha2[i], bf2f(h2u[(size_t)csr[i] * 32 + c]), acc);
    out[(size_t)n * 32 + c] = acc + b2[c];
}

// ---------------- launch ----------------

extern "C" void kernel_launch(void* const* d_in, const int* in_sizes, int n_in,
                              void* d_out, int out_size, void* d_ws, size_t ws_size,
                              hipStream_t stream) {
    const float* x   = (const float*)d_in[0];
    const int*   ei  = (const int*)d_in[1];
    const float* W1  = (const float*)d_in[2];
    const float* a1s = (const float*)d_in[3];
    const float* a1d = (const float*)d_in[4];
    const float* b1  = (const float*)d_in[5];
    const float* W2  = (const float*)d_in[6];
    const float* a2s = (const float*)d_in[7];
    const float* a2d = (const float*)d_in[8];
    const float* b2  = (const float*)d_in[9];
    float* out = (float*)d_out;

    char* w = (char*)d_ws;
    float* hr     = (float*)w;  w += (size_t)N_NODES * 256 * 4;
    ushort* h1u   = (ushort*)w; w += (size_t)N_NODES * 256 * 2;
    ushort* xbf   = (ushort*)w; w += (size_t)N_RT * 4 * 64 * 8 * 2;
    ushort* W1f   = (ushort*)w; w += (size_t)16 * 4 * 64 * 8 * 2;
    float* AT     = (float*)w;  w += (size_t)16 * 128 * 4;
    ushort* h2u   = (ushort*)w; w += (size_t)N_NODES * 32 * 2;
    float* s1s    = (float*)w;  w += (size_t)N_NODES * 8 * 4;
    float* s1d    = (float*)w;  w += (size_t)N_NODES * 8 * 4;
    float* s2s    = (float*)w;  w += (size_t)N_NODES * 4;
    float* s2d    = (float*)w;  w += (size_t)N_NODES * 4;
    __half* alpha = (__half*)w; w += (size_t)E_TOT * 8 * 2;
    float* alpha2 = (float*)w;  w += (size_t)E_TOT * 4;
    int* cnt    = (int*)w; w += (size_t)N_NODES * 4;
    int* offs   = (int*)w; w += (size_t)(N_NODES + 1) * 4;
    int* cursor = (int*)w; w += (size_t)(N_NODES + 4) * 4;
    int* bsum   = (int*)w; w += (size_t)NB_SCAN * 4;
    int* boffs  = (int*)w; w += (size_t)NB_SCAN * 4;
    int* csr    = (int*)w; w += (size_t)E_TOT * 4;

    hipMemsetAsync(cnt, 0, (size_t)N_NODES * 4, stream);
    hist_k<<<(E_TOT + 255) / 256, 256, 0, stream>>>(ei, cnt);
    scanA_k<<<NB_SCAN, 256, 0, stream>>>(cnt, offs, bsum);
    scanB_k<<<1, 256, 0, stream>>>(bsum, boffs);
    scanC_k<<<NB_SCAN, 256, 0, stream>>>(boffs, offs, cursor);
    scat_k<<<(E_TOT + 255) / 256, 256, 0, stream>>>(ei, cursor, csr);

    w1a_k<<<8, 256, 0, stream>>>(W1, a1s, a1d, AT);
    w1f_k<<<16, 256, 0, stream>>>(W1, W1f);
    prep_k<<<(N_NODES + 63) / 64, 256, 0, stream>>>(x, AT, xbf, s1s, s1d);
    gemm1_k<<<(N_RT + 3) / 4, 256, 0, stream>>>(xbf, W1f, h1u);
    stats1_k<<<(N_NODES + 3) / 4, 256, 0, stream>>>(csr, offs, s1s, s1d, alpha);
    agg1_k<<<(N_NODES + 3) / 4, 256, 0, stream>>>(csr, offs, h1u, alpha, b1, hr);
    gemm2_k<<<(N_NODES + 31) / 32, 256, 0, stream>>>(hr, W2, a2s, a2d, h2u, s2s, s2d);
    stats2_k<<<(N_NODES + 3) / 4, 256, 0, stream>>>(csr, offs, s2s, s2d, alpha2);
    agg2_k<<<(N_NODES + 7) / 8, 256, 0, stream>>>(csr, offs, h2u, alpha2, b2, out);
}